// Round 4
// baseline (3323.531 us; speedup 1.0000x reference)
//
#include <hip/hip_runtime.h>
#include <hip/hip_fp16.h>

#define B_  256
#define T_  512
#define I_  64
#define H_  128
#define G_  384
#define HC  256

// Workspace byte offsets (total ~168.1 MB)
#define O_OUT0 0ull                    // fp16 [B][T][2H] = 67,108,864
#define O_XW1  67108864ull             // fp16 [B][T][3H] = 100,663,296
#define O_WP   167772160ull            // packed half2 Wih1b, 196,608
#define O_H1F  (O_WP + 196608ull)      // f32 [B][H]

typedef _Float16 h8 __attribute__((ext_vector_type(8)));
typedef _Float16 h4 __attribute__((ext_vector_type(4)));
typedef float    f4 __attribute__((ext_vector_type(4)));

__device__ __forceinline__ float sigm(float x)   { return 1.f / (1.f + __expf(-x)); }
__device__ __forceinline__ float tanh_f(float x) { return 1.f - 2.f / (1.f + __expf(2.f * x)); }

// LDS-only barrier: waits lgkmcnt(0) (DS ops) but NOT vmcnt — global stores
// (out0, no in-kernel reader) and in-flight prefetch loads cross freely.
__device__ __forceinline__ void bar_lds() {
    asm volatile("s_waitcnt lgkmcnt(0)\n\ts_barrier" ::: "memory");
}

__device__ __forceinline__ h8 load_w8(const float* src) {
    f4 a = *(const f4*)src;
    f4 b = *(const f4*)(src + 4);
    h8 v;
    v[0]=(_Float16)a[0]; v[1]=(_Float16)a[1]; v[2]=(_Float16)a[2]; v[3]=(_Float16)a[3];
    v[4]=(_Float16)b[0]; v[5]=(_Float16)b[1]; v[6]=(_Float16)b[2]; v[7]=(_Float16)b[3];
    return v;
}

// Transpose+pack a [384][K] fp32 weight into [K/2][384] half2 (for final_k).
__global__ void pack_wT(const float* __restrict__ W, __half2* __restrict__ dst,
                        int K, int total) {
    int i = blockIdx.x * 256 + threadIdx.x;
    if (i >= total) return;
    int c = i % G_;
    int k2 = i / G_;
    dst[i] = __halves2half2(__float2half(W[c * K + 2 * k2]),
                            __float2half(W[c * K + 2 * k2 + 1]));
}

// ---------------- Layer-0 scan ----------------
// 16 batch rows/block, dirs via blockIdx.y. 4 waves; wave w owns hidden units
// 32w..32w+31 (2 col-tiles per gate). Gates + h-state in registers; per step:
// 6 b128 A-frag reads + h/x writebacks, ONE LDS-only barrier.
__launch_bounds__(256, 1)
__global__ void scan_l0(const float* __restrict__ x,
                        const float* __restrict__ Wih_f, const float* __restrict__ Whh_f,
                        const float* __restrict__ bih_f, const float* __restrict__ bhh_f,
                        const float* __restrict__ Wih_b, const float* __restrict__ Whh_b,
                        const float* __restrict__ bih_b, const float* __restrict__ bhh_b,
                        _Float16* __restrict__ out0) {
    __shared__ _Float16 s_hA[2][16][136];   // dbuf fp16 h (A-layout)
    __shared__ _Float16 s_x[2][16][80];     // dbuf fp16 x(t)

    const int tid  = threadIdx.x;
    const int lane = tid & 63;
    const int w    = tid >> 6;          // wave 0..3
    const int ln15 = lane & 15;
    const int lq   = lane >> 4;         // 0..3
    const int dir  = blockIdx.y;
    const int b0   = blockIdx.x * 16;

    const float* Wih = dir ? Wih_b : Wih_f;
    const float* Whh = dir ? Whh_b : Whh_f;
    const float* bih = dir ? bih_b : bih_f;
    const float* bhh = dir ? bhh_b : bhh_f;

    // B fragments: [gate][colTile u][kt]; unit col = 32w + 16u + ln15
    h8 bh[3][2][4], bx[3][2][2];
    float seedR[2], seedZ[2], bihN[2], bhhN[2];
#pragma unroll
    for (int u = 0; u < 2; u++) {
        int c = 32 * w + 16 * u + ln15;
        seedR[u] = bih[c] + bhh[c];
        seedZ[u] = bih[H_ + c] + bhh[H_ + c];
        bihN[u] = bih[2 * H_ + c];
        bhhN[u] = bhh[2 * H_ + c];
#pragma unroll
        for (int g = 0; g < 3; g++) {
            int n = g * H_ + c;
#pragma unroll
            for (int kt = 0; kt < 4; kt++) bh[g][u][kt] = load_w8(Whh + (size_t)n * H_ + kt * 32 + lq * 8);
#pragma unroll
            for (int kt = 0; kt < 2; kt++) bx[g][u][kt] = load_w8(Wih + (size_t)n * I_ + kt * 32 + lq * 8);
        }
    }

    const int xr = tid >> 4, xc = (tid & 15) * 4;
    {   // zero h buf0, stage x(t=0)
        _Float16* pa = &s_hA[0][0][0];
        for (int i = tid; i < 16 * 136; i += 256) pa[i] = (_Float16)0.f;
        int tt0 = dir ? (T_ - 1) : 0;
        f4 xv = *(const f4*)(x + ((size_t)(b0 + xr) * T_ + tt0) * I_ + xc);
        h4 hv; hv[0]=(_Float16)xv[0]; hv[1]=(_Float16)xv[1]; hv[2]=(_Float16)xv[2]; hv[3]=(_Float16)xv[3];
        *(h4*)&s_x[0][xr][xc] = hv;
    }
    float hF[2][4] = {};
    __syncthreads();

    for (int t = 0; t < T_; ++t) {
        const int buf = t & 1;
        const int tt = dir ? (T_ - 1 - t) : t;
        // A fragments
        h8 ah[4], axf[2];
#pragma unroll
        for (int kt = 0; kt < 4; kt++) ah[kt] = *(const h8*)&s_hA[buf][ln15][kt * 32 + lq * 8];
#pragma unroll
        for (int kt = 0; kt < 2; kt++) axf[kt] = *(const h8*)&s_x[buf][ln15][kt * 32 + lq * 8];
        // prefetch x(t+1) (issued before gate stores -> partial vmcnt wait)
        f4 xpre;
        if (t < T_ - 1) {
            int tn = dir ? (tt - 1) : (tt + 1);
            xpre = *(const f4*)(x + ((size_t)(b0 + xr) * T_ + tn) * I_ + xc);
        }
        f4 aR[2], aZ[2], aXn[2], aHn[2];
#pragma unroll
        for (int u = 0; u < 2; u++) {
            aR[u]  = (f4){seedR[u], seedR[u], seedR[u], seedR[u]};
            aZ[u]  = (f4){seedZ[u], seedZ[u], seedZ[u], seedZ[u]};
            aXn[u] = (f4){bihN[u], bihN[u], bihN[u], bihN[u]};
            aHn[u] = (f4){bhhN[u], bhhN[u], bhhN[u], bhhN[u]};
        }
#pragma unroll
        for (int u = 0; u < 2; u++) {
#pragma unroll
            for (int kt = 0; kt < 4; kt++) {
                aR[u]  = __builtin_amdgcn_mfma_f32_16x16x32_f16(ah[kt], bh[0][u][kt], aR[u], 0, 0, 0);
                aZ[u]  = __builtin_amdgcn_mfma_f32_16x16x32_f16(ah[kt], bh[1][u][kt], aZ[u], 0, 0, 0);
                aHn[u] = __builtin_amdgcn_mfma_f32_16x16x32_f16(ah[kt], bh[2][u][kt], aHn[u], 0, 0, 0);
            }
#pragma unroll
            for (int kt = 0; kt < 2; kt++) {
                aR[u]  = __builtin_amdgcn_mfma_f32_16x16x32_f16(axf[kt], bx[0][u][kt], aR[u], 0, 0, 0);
                aZ[u]  = __builtin_amdgcn_mfma_f32_16x16x32_f16(axf[kt], bx[1][u][kt], aZ[u], 0, 0, 0);
                aXn[u] = __builtin_amdgcn_mfma_f32_16x16x32_f16(axf[kt], bx[2][u][kt], aXn[u], 0, 0, 0);
            }
        }
        // gates in registers
#pragma unroll
        for (int u = 0; u < 2; u++) {
            int col = 32 * w + 16 * u + ln15;
#pragma unroll
            for (int reg = 0; reg < 4; reg++) {
                float r = sigm(aR[u][reg]);
                float z = sigm(aZ[u][reg]);
                float n = tanh_f(aXn[u][reg] + r * aHn[u][reg]);
                float h = n + z * (hF[u][reg] - n);
                hF[u][reg] = h;
                int brow = lq * 4 + reg;
                out0[((size_t)(b0 + brow) * T_ + tt) * HC + dir * H_ + col] = (_Float16)h;
                s_hA[buf ^ 1][brow][col] = (_Float16)h;
            }
        }
        if (t < T_ - 1) {
            h4 hv; hv[0]=(_Float16)xpre[0]; hv[1]=(_Float16)xpre[1]; hv[2]=(_Float16)xpre[2]; hv[3]=(_Float16)xpre[3];
            *(h4*)&s_x[buf ^ 1][xr][xc] = hv;
        }
        bar_lds();
    }
}

// ---------------- MFMA GEMM: xw1 = out0 @ Wih1f^T + bih1f ----------------
__launch_bounds__(256)
__global__ void gemm_xw1(const _Float16* __restrict__ A,  // [M][256]
                         const float* __restrict__ Wf,    // [384][256]
                         const float* __restrict__ bias,
                         _Float16* __restrict__ C) {      // [M][384]
    __shared__ _Float16 sA[128][40];
    __shared__ _Float16 sB[128][40];
    const int tid  = threadIdx.x;
    const int lane = tid & 63;
    const int w    = tid >> 6;
    const int wm   = w & 1, wn = w >> 1;
    const int ln15 = lane & 15, lq = lane >> 4;
    const size_t m0 = (size_t)blockIdx.x * 128;
    const int    n0 = blockIdx.y * 128;
    const int sr = tid >> 1, sc = (tid & 1) * 16;

    f4 acc[4][4] = {};

    for (int k0 = 0; k0 < 256; k0 += 32) {
        f4 av0 = *(const f4*)(A + (m0 + sr) * 256 + k0 + sc);
        f4 av1 = *(const f4*)(A + (m0 + sr) * 256 + k0 + sc + 8);
        const float* bsrc = Wf + (size_t)(n0 + sr) * 256 + k0 + sc;
        f4 b0v = *(const f4*)bsrc;
        f4 b1v = *(const f4*)(bsrc + 4);
        f4 b2v = *(const f4*)(bsrc + 8);
        f4 b3v = *(const f4*)(bsrc + 12);
        *(f4*)&sA[sr][sc]     = av0;
        *(f4*)&sA[sr][sc + 8] = av1;
        _Float16* bd = &sB[sr][sc];
        bd[0]=(_Float16)b0v[0]; bd[1]=(_Float16)b0v[1]; bd[2]=(_Float16)b0v[2]; bd[3]=(_Float16)b0v[3];
        bd[4]=(_Float16)b1v[0]; bd[5]=(_Float16)b1v[1]; bd[6]=(_Float16)b1v[2]; bd[7]=(_Float16)b1v[3];
        bd[8]=(_Float16)b2v[0]; bd[9]=(_Float16)b2v[1]; bd[10]=(_Float16)b2v[2]; bd[11]=(_Float16)b2v[3];
        bd[12]=(_Float16)b3v[0]; bd[13]=(_Float16)b3v[1]; bd[14]=(_Float16)b3v[2]; bd[15]=(_Float16)b3v[3];
        __syncthreads();
        h8 af[4], bf[4];
#pragma unroll
        for (int mt = 0; mt < 4; mt++) af[mt] = *(const h8*)&sA[wm * 64 + mt * 16 + ln15][lq * 8];
#pragma unroll
        for (int nt = 0; nt < 4; nt++) bf[nt] = *(const h8*)&sB[wn * 64 + nt * 16 + ln15][lq * 8];
#pragma unroll
        for (int mt = 0; mt < 4; mt++)
#pragma unroll
            for (int nt = 0; nt < 4; nt++)
                acc[mt][nt] = __builtin_amdgcn_mfma_f32_16x16x32_f16(af[mt], bf[nt], acc[mt][nt], 0, 0, 0);
        __syncthreads();
    }
#pragma unroll
    for (int nt = 0; nt < 4; nt++) {
        int col = n0 + wn * 64 + nt * 16 + ln15;
        float bb = bias[col];
#pragma unroll
        for (int mt = 0; mt < 4; mt++) {
            size_t row = m0 + wm * 64 + mt * 16 + lq * 4;
#pragma unroll
            for (int reg = 0; reg < 4; reg++)
                C[(row + reg) * G_ + col] = (_Float16)(acc[mt][nt][reg] + bb);
        }
    }
}

// ---------------- Layer-1 fwd scan ----------------
__launch_bounds__(256, 1)
__global__ void scan_l1(const _Float16* __restrict__ xw1,
                        const float* __restrict__ Whh,   // Whh1f [384][128]
                        const float* __restrict__ bhh,
                        float* __restrict__ h1f) {
    __shared__ _Float16 s_hA[2][16][136];

    const int tid  = threadIdx.x;
    const int lane = tid & 63;
    const int w    = tid >> 6;
    const int ln15 = lane & 15;
    const int lq   = lane >> 4;
    const int b0   = blockIdx.x * 16;

    h8 bh[3][2][4];
    float bhhF[3][2];
#pragma unroll
    for (int u = 0; u < 2; u++) {
        int c = 32 * w + 16 * u + ln15;
#pragma unroll
        for (int g = 0; g < 3; g++) {
            int n = g * H_ + c;
            bhhF[g][u] = bhh[n];
#pragma unroll
            for (int kt = 0; kt < 4; kt++) bh[g][u][kt] = load_w8(Whh + (size_t)n * H_ + kt * 32 + lq * 8);
        }
    }
    {
        _Float16* pa = &s_hA[0][0][0];
        for (int i = tid; i < 16 * 136; i += 256) pa[i] = (_Float16)0.f;
    }
    // xw base pointers per batch reg (C-layout direct loads); col offset u*16
    const _Float16* xb[4];
#pragma unroll
    for (int reg = 0; reg < 4; reg++)
        xb[reg] = xw1 + (size_t)(b0 + lq * 4 + reg) * T_ * G_ + 32 * w + ln15;
    float xwc[3][2][4];
#pragma unroll
    for (int g = 0; g < 3; g++)
#pragma unroll
        for (int u = 0; u < 2; u++)
#pragma unroll
            for (int reg = 0; reg < 4; reg++)
                xwc[g][u][reg] = (float)xb[reg][g * H_ + u * 16];   // t=0
    float hF[2][4] = {};
    __syncthreads();

    for (int t = 0; t < T_; ++t) {
        const int buf = t & 1;
        h8 ah[4];
#pragma unroll
        for (int kt = 0; kt < 4; kt++) ah[kt] = *(const h8*)&s_hA[buf][ln15][kt * 32 + lq * 8];
        // prefetch xw(t+1)
        float xwn[3][2][4];
        if (t < T_ - 1) {
#pragma unroll
            for (int g = 0; g < 3; g++)
#pragma unroll
                for (int u = 0; u < 2; u++)
#pragma unroll
                    for (int reg = 0; reg < 4; reg++)
                        xwn[g][u][reg] = (float)xb[reg][(size_t)(t + 1) * G_ + g * H_ + u * 16];
        }
        f4 aH[3][2];
#pragma unroll
        for (int g = 0; g < 3; g++)
#pragma unroll
            for (int u = 0; u < 2; u++)
                aH[g][u] = (f4){bhhF[g][u], bhhF[g][u], bhhF[g][u], bhhF[g][u]};
#pragma unroll
        for (int u = 0; u < 2; u++)
#pragma unroll
            for (int kt = 0; kt < 4; kt++) {
                aH[0][u] = __builtin_amdgcn_mfma_f32_16x16x32_f16(ah[kt], bh[0][u][kt], aH[0][u], 0, 0, 0);
                aH[1][u] = __builtin_amdgcn_mfma_f32_16x16x32_f16(ah[kt], bh[1][u][kt], aH[1][u], 0, 0, 0);
                aH[2][u] = __builtin_amdgcn_mfma_f32_16x16x32_f16(ah[kt], bh[2][u][kt], aH[2][u], 0, 0, 0);
            }
#pragma unroll
        for (int u = 0; u < 2; u++) {
            int col = 32 * w + 16 * u + ln15;
#pragma unroll
            for (int reg = 0; reg < 4; reg++) {
                float r = sigm(xwc[0][u][reg] + aH[0][u][reg]);
                float z = sigm(xwc[1][u][reg] + aH[1][u][reg]);
                float n = tanh_f(xwc[2][u][reg] + r * aH[2][u][reg]);
                float h = n + z * (hF[u][reg] - n);
                hF[u][reg] = h;
                s_hA[buf ^ 1][lq * 4 + reg][col] = (_Float16)h;
            }
        }
        if (t < T_ - 1) {
#pragma unroll
            for (int g = 0; g < 3; g++)
#pragma unroll
                for (int u = 0; u < 2; u++)
#pragma unroll
                    for (int reg = 0; reg < 4; reg++)
                        xwc[g][u][reg] = xwn[g][u][reg];
        }
        bar_lds();
    }
#pragma unroll
    for (int u = 0; u < 2; u++)
#pragma unroll
        for (int reg = 0; reg < 4; reg++)
            h1f[(size_t)(b0 + lq * 4 + reg) * H_ + 32 * w + 16 * u + ln15] = hF[u][reg];
}

// ---------------- Tail: layer-1 bwd single step + relu + FC ----------------
__launch_bounds__(384)
__global__ void final_k(const _Float16* __restrict__ out0,
                        const float* __restrict__ h1f,
                        const __half2* __restrict__ w1b,   // packed Wih1b [128][384]
                        const float* __restrict__ bih1b, const float* __restrict__ bhh1b,
                        const float* __restrict__ fcw, const float* __restrict__ fcb,
                        float* __restrict__ out) {
    __shared__ __align__(16) float s_x1[HC];
    __shared__ __align__(16) float s_xw[G_];
    __shared__ __align__(16) float s_hc[HC];
    __shared__ float s_red[8];
    const int tid = threadIdx.x;
    const int b = blockIdx.x;
    if (tid < HC)
        s_x1[tid] = (float)out0[((size_t)b * T_ + (T_ - 1)) * HC + tid];
    __syncthreads();
    {
        float acc0 = 0.f, acc1 = 0.f;
        const float2* xv = (const float2*)s_x1;
#pragma unroll 8
        for (int k2 = 0; k2 < 128; k2 += 2) {
            float2 w0 = __half22float2(w1b[k2 * G_ + tid]);
            float2 w1 = __half22float2(w1b[(k2 + 1) * G_ + tid]);
            float2 a0 = xv[k2], a1 = xv[k2 + 1];
            acc0 += a0.x * w0.x + a0.y * w0.y;
            acc1 += a1.x * w1.x + a1.y * w1.y;
        }
        s_xw[tid] = bih1b[tid] + acc0 + acc1;
    }
    __syncthreads();
    if (tid < H_) {
        int j = tid;
        float rg = sigm(s_xw[j] + bhh1b[j]);
        float zg = sigm(s_xw[H_ + j] + bhh1b[H_ + j]);
        float ng = tanh_f(s_xw[2 * H_ + j] + rg * bhh1b[2 * H_ + j]);
        float hb = (1.f - zg) * ng;
        s_hc[H_ + j] = fmaxf(hb, 0.f);
        s_hc[j] = fmaxf(h1f[(size_t)b * H_ + j], 0.f);
    }
    __syncthreads();
    if (tid < HC) {
        float hv = s_hc[tid];
        float p0 = hv * fcw[tid];
        float p1 = hv * fcw[HC + tid];
#pragma unroll
        for (int off = 32; off; off >>= 1) {
            p0 += __shfl_down(p0, off);
            p1 += __shfl_down(p1, off);
        }
        if ((tid & 63) == 0) { s_red[(tid >> 6) * 2] = p0; s_red[(tid >> 6) * 2 + 1] = p1; }
    }
    __syncthreads();
    if (tid == 0) {
        out[b * 2 + 0] = fcb[0] + s_red[0] + s_red[2] + s_red[4] + s_red[6];
        out[b * 2 + 1] = fcb[1] + s_red[1] + s_red[3] + s_red[5] + s_red[7];
    }
}

extern "C" void kernel_launch(void* const* d_in, const int* in_sizes, int n_in,
                              void* d_out, int out_size, void* d_ws, size_t ws_size,
                              hipStream_t stream) {
    (void)in_sizes; (void)n_in; (void)out_size; (void)ws_size;
    const float* x     = (const float*)d_in[0];
    const float* Wih0f = (const float*)d_in[1];
    const float* Whh0f = (const float*)d_in[2];
    const float* bih0f = (const float*)d_in[3];
    const float* bhh0f = (const float*)d_in[4];
    const float* Wih0b = (const float*)d_in[5];
    const float* Whh0b = (const float*)d_in[6];
    const float* bih0b = (const float*)d_in[7];
    const float* bhh0b = (const float*)d_in[8];
    const float* Wih1f = (const float*)d_in[9];
    const float* Whh1f = (const float*)d_in[10];
    const float* bih1f = (const float*)d_in[11];
    const float* bhh1f = (const float*)d_in[12];
    const float* Wih1b = (const float*)d_in[13];
    const float* bih1b = (const float*)d_in[15];
    const float* bhh1b = (const float*)d_in[16];
    const float* fcw   = (const float*)d_in[17];
    const float* fcb   = (const float*)d_in[18];

    char* ws = (char*)d_ws;
    _Float16* out0 = (_Float16*)(ws + O_OUT0);
    _Float16* xw1  = (_Float16*)(ws + O_XW1);
    __half2*  wp   = (__half2*)(ws + O_WP);
    float*    h1f  = (float*)(ws + O_H1F);
    float*    out  = (float*)d_out;

    pack_wT<<<192, 256, 0, stream>>>(Wih1b, wp, 256, 49152);

    scan_l0<<<dim3(16, 2), 256, 0, stream>>>(x, Wih0f, Whh0f, bih0f, bhh0f,
                                             Wih0b, Whh0b, bih0b, bhh0b, out0);

    gemm_xw1<<<dim3(1024, 3), 256, 0, stream>>>(out0, Wih1f, bih1f, xw1);

    scan_l1<<<16, 256, 0, stream>>>(xw1, Whh1f, bhh1f, h1f);

    final_k<<<256, 384, 0, stream>>>(out0, h1f, wp, bih1b, bhh1b, fcw, fcb, out);
}

// Round 5
// 1520.394 us; speedup vs baseline: 2.1860x; 2.1860x over previous
//
#include <hip/hip_runtime.h>
#include <hip/hip_fp16.h>

#define B_  256
#define T_  512
#define I_  64
#define H_  128
#define G_  384
#define HC  256

// Workspace byte offsets (total ~168.1 MB)
#define O_OUT0 0ull                    // fp16 [B][T][2H] = 67,108,864
#define O_XW1  67108864ull             // fp16 [B][T][3H] = 100,663,296
#define O_WP   167772160ull            // packed half2 Wih1b, 196,608
#define O_H1F  (O_WP + 196608ull)      // f32 [B][H]

typedef _Float16 h8 __attribute__((ext_vector_type(8)));
typedef float    f4 __attribute__((ext_vector_type(4)));

__device__ __forceinline__ float sigm(float x)   { return 1.f / (1.f + __expf(-x)); }
__device__ __forceinline__ float tanh_f(float x) { return 1.f - 2.f / (1.f + __expf(2.f * x)); }

// LDS-only barrier: waits lgkmcnt(0) (DS ops) but NOT vmcnt — global stores
// (out0: no in-kernel reader) and in-flight prefetch loads cross freely.
__device__ __forceinline__ void bar_lds() {
    asm volatile("s_waitcnt lgkmcnt(0)\n\ts_barrier" ::: "memory");
}

__device__ __forceinline__ h8 load_w8(const float* src) {
    f4 a = *(const f4*)src;
    f4 b = *(const f4*)(src + 4);
    h8 v;
    v[0]=(_Float16)a[0]; v[1]=(_Float16)a[1]; v[2]=(_Float16)a[2]; v[3]=(_Float16)a[3];
    v[4]=(_Float16)b[0]; v[5]=(_Float16)b[1]; v[6]=(_Float16)b[2]; v[7]=(_Float16)b[3];
    return v;
}

// Transpose+pack a [384][K] fp32 weight into [K/2][384] half2 (for final_k).
__global__ void pack_wT(const float* __restrict__ W, __half2* __restrict__ dst,
                        int K, int total) {
    int i = blockIdx.x * 256 + threadIdx.x;
    if (i >= total) return;
    int c = i % G_;
    int k2 = i / G_;
    dst[i] = __halves2half2(__float2half(W[c * K + 2 * k2]),
                            __float2half(W[c * K + 2 * k2 + 1]));
}

// ---------------- Layer-0 scan (R3 structure + LDS-only barrier) ----------------
// 16 batch rows/block, dirs via blockIdx.y. 8 waves; wave w owns hidden units
// 16w..16w+15 with tiles (r,z,n): gate math + h-state in registers. 88 VGPR.
__launch_bounds__(512, 1)
__global__ void scan_l0(const float* __restrict__ x,
                        const float* __restrict__ Wih_f, const float* __restrict__ Whh_f,
                        const float* __restrict__ bih_f, const float* __restrict__ bhh_f,
                        const float* __restrict__ Wih_b, const float* __restrict__ Whh_b,
                        const float* __restrict__ bih_b, const float* __restrict__ bhh_b,
                        _Float16* __restrict__ out0) {
    __shared__ _Float16 s_hA[2][16][136];   // dbuf fp16 h (A-layout)
    __shared__ _Float16 s_x[2][16][80];     // dbuf fp16 x(t)

    const int tid  = threadIdx.x;
    const int lane = tid & 63;
    const int w    = tid >> 6;          // wave 0..7
    const int ln15 = lane & 15;
    const int lq   = lane >> 4;         // 0..3
    const int dir  = blockIdx.y;
    const int b0   = blockIdx.x * 16;
    const int col  = 16 * w + ln15;     // hidden unit owned by this lane

    const float* Wih = dir ? Wih_b : Wih_f;
    const float* Whh = dir ? Whh_b : Whh_f;
    const float* bih = dir ? bih_b : bih_f;
    const float* bhh = dir ? bhh_b : bhh_f;

    // Register-resident B fragments, gate-permuted
    h8 bh[3][4], bx[3][2];
    float seedR, seedZ, bihN, bhhN;
    {
        seedR = bih[col] + bhh[col];
        seedZ = bih[H_ + col] + bhh[H_ + col];
        bihN  = bih[2 * H_ + col];
        bhhN  = bhh[2 * H_ + col];
#pragma unroll
        for (int g = 0; g < 3; g++) {
            int n = g * H_ + col;
#pragma unroll
            for (int kt = 0; kt < 4; kt++) bh[g][kt] = load_w8(Whh + (size_t)n * H_ + kt * 32 + lq * 8);
#pragma unroll
            for (int kt = 0; kt < 2; kt++) bx[g][kt] = load_w8(Wih + (size_t)n * I_ + kt * 32 + lq * 8);
        }
    }

    const int xr = tid >> 5, xc = (tid & 31) * 2;
    {   // zero h buf0, stage x(t=0) into buf0
        _Float16* pa = &s_hA[0][0][0];
        for (int i = tid; i < 16 * 136; i += 512) pa[i] = (_Float16)0.f;
        int tt0 = dir ? (T_ - 1) : 0;
        float2 xv = *(const float2*)(x + ((size_t)(b0 + xr) * T_ + tt0) * I_ + xc);
        s_x[0][xr][xc]     = (_Float16)xv.x;
        s_x[0][xr][xc + 1] = (_Float16)xv.y;
    }
    float hF[4] = {0.f, 0.f, 0.f, 0.f};
    __syncthreads();

    for (int t = 0; t < T_; ++t) {
        const int buf = t & 1;
        const int tt = dir ? (T_ - 1 - t) : t;
        // A fragments (h + x) from current buffer
        h8 ah[4], axf[2];
#pragma unroll
        for (int kt = 0; kt < 4; kt++) ah[kt] = *(const h8*)&s_hA[buf][ln15][kt * 32 + lq * 8];
#pragma unroll
        for (int kt = 0; kt < 2; kt++) axf[kt] = *(const h8*)&s_x[buf][ln15][kt * 32 + lq * 8];
        // prefetch x(t+1)
        float2 xpre;
        if (t < T_ - 1) {
            int tn = dir ? (tt - 1) : (tt + 1);
            xpre = *(const float2*)(x + ((size_t)(b0 + xr) * T_ + tn) * I_ + xc);
        }
        f4 aR = (f4){seedR, seedR, seedR, seedR};
        f4 aZ = (f4){seedZ, seedZ, seedZ, seedZ};
        f4 aXn = (f4){bihN, bihN, bihN, bihN};
        f4 aHn = (f4){bhhN, bhhN, bhhN, bhhN};
#pragma unroll
        for (int kt = 0; kt < 4; kt++) {
            aR  = __builtin_amdgcn_mfma_f32_16x16x32_f16(ah[kt], bh[0][kt], aR, 0, 0, 0);
            aZ  = __builtin_amdgcn_mfma_f32_16x16x32_f16(ah[kt], bh[1][kt], aZ, 0, 0, 0);
            aHn = __builtin_amdgcn_mfma_f32_16x16x32_f16(ah[kt], bh[2][kt], aHn, 0, 0, 0);
        }
#pragma unroll
        for (int kt = 0; kt < 2; kt++) {
            aR  = __builtin_amdgcn_mfma_f32_16x16x32_f16(axf[kt], bx[0][kt], aR, 0, 0, 0);
            aZ  = __builtin_amdgcn_mfma_f32_16x16x32_f16(axf[kt], bx[1][kt], aZ, 0, 0, 0);
            aXn = __builtin_amdgcn_mfma_f32_16x16x32_f16(axf[kt], bx[2][kt], aXn, 0, 0, 0);
        }
        // gates fully in registers (C layout: row=lq*4+reg, col=unit)
#pragma unroll
        for (int reg = 0; reg < 4; reg++) {
            float r = sigm(aR[reg]);
            float z = sigm(aZ[reg]);
            float n = tanh_f(aXn[reg] + r * aHn[reg]);
            float h = n + z * (hF[reg] - n);
            hF[reg] = h;
            int brow = lq * 4 + reg;
            out0[((size_t)(b0 + brow) * T_ + tt) * HC + dir * H_ + col] = (_Float16)h;
            s_hA[buf ^ 1][brow][col] = (_Float16)h;
        }
        if (t < T_ - 1) {
            s_x[buf ^ 1][xr][xc]     = (_Float16)xpre.x;
            s_x[buf ^ 1][xr][xc + 1] = (_Float16)xpre.y;
        }
        bar_lds();
    }
}

// ---------------- MFMA GEMM: xw1 = out0 @ Wih1f^T + bih1f ----------------
__launch_bounds__(256)
__global__ void gemm_xw1(const _Float16* __restrict__ A,  // [M][256]
                         const float* __restrict__ Wf,    // [384][256]
                         const float* __restrict__ bias,
                         _Float16* __restrict__ C) {      // [M][384]
    __shared__ _Float16 sA[128][40];
    __shared__ _Float16 sB[128][40];
    const int tid  = threadIdx.x;
    const int lane = tid & 63;
    const int w    = tid >> 6;
    const int wm   = w & 1, wn = w >> 1;
    const int ln15 = lane & 15, lq = lane >> 4;
    const size_t m0 = (size_t)blockIdx.x * 128;
    const int    n0 = blockIdx.y * 128;
    const int sr = tid >> 1, sc = (tid & 1) * 16;

    f4 acc[4][4] = {};

    for (int k0 = 0; k0 < 256; k0 += 32) {
        f4 av0 = *(const f4*)(A + (m0 + sr) * 256 + k0 + sc);
        f4 av1 = *(const f4*)(A + (m0 + sr) * 256 + k0 + sc + 8);
        const float* bsrc = Wf + (size_t)(n0 + sr) * 256 + k0 + sc;
        f4 b0v = *(const f4*)bsrc;
        f4 b1v = *(const f4*)(bsrc + 4);
        f4 b2v = *(const f4*)(bsrc + 8);
        f4 b3v = *(const f4*)(bsrc + 12);
        *(f4*)&sA[sr][sc]     = av0;
        *(f4*)&sA[sr][sc + 8] = av1;
        _Float16* bd = &sB[sr][sc];
        bd[0]=(_Float16)b0v[0]; bd[1]=(_Float16)b0v[1]; bd[2]=(_Float16)b0v[2]; bd[3]=(_Float16)b0v[3];
        bd[4]=(_Float16)b1v[0]; bd[5]=(_Float16)b1v[1]; bd[6]=(_Float16)b1v[2]; bd[7]=(_Float16)b1v[3];
        bd[8]=(_Float16)b2v[0]; bd[9]=(_Float16)b2v[1]; bd[10]=(_Float16)b2v[2]; bd[11]=(_Float16)b2v[3];
        bd[12]=(_Float16)b3v[0]; bd[13]=(_Float16)b3v[1]; bd[14]=(_Float16)b3v[2]; bd[15]=(_Float16)b3v[3];
        __syncthreads();
        h8 af[4], bf[4];
#pragma unroll
        for (int mt = 0; mt < 4; mt++) af[mt] = *(const h8*)&sA[wm * 64 + mt * 16 + ln15][lq * 8];
#pragma unroll
        for (int nt = 0; nt < 4; nt++) bf[nt] = *(const h8*)&sB[wn * 64 + nt * 16 + ln15][lq * 8];
#pragma unroll
        for (int mt = 0; mt < 4; mt++)
#pragma unroll
            for (int nt = 0; nt < 4; nt++)
                acc[mt][nt] = __builtin_amdgcn_mfma_f32_16x16x32_f16(af[mt], bf[nt], acc[mt][nt], 0, 0, 0);
        __syncthreads();
    }
#pragma unroll
    for (int nt = 0; nt < 4; nt++) {
        int col = n0 + wn * 64 + nt * 16 + ln15;
        float bb = bias[col];
#pragma unroll
        for (int mt = 0; mt < 4; mt++) {
            size_t row = m0 + wm * 64 + mt * 16 + lq * 4;
#pragma unroll
            for (int reg = 0; reg < 4; reg++)
                C[(row + reg) * G_ + col] = (_Float16)(acc[mt][nt][reg] + bb);
        }
    }
}

// ---------------- Layer-1 fwd scan: LDS ring for xw, coalesced staging ----------------
// 512 threads, 16 blocks. Ring slot parity: consume slot t&1 (written at t-1
// from regs loaded at t-2). Two register sets (pfA even-issued, pfB odd) —
// no register rotation, unroll by 2. Wait for a load lands one full step later.
__launch_bounds__(512, 1)
__global__ void scan_l1(const _Float16* __restrict__ xw1,
                        const float* __restrict__ Whh,   // Whh1f [384][128]
                        const float* __restrict__ bhh,
                        float* __restrict__ h1f) {
    __shared__ _Float16 s_hA[2][16][136];
    __shared__ _Float16 s_xw[2][16][400];   // ring; 400-half row pad => quarters 8 banks apart

    const int tid  = threadIdx.x;
    const int lane = tid & 63;
    const int w    = tid >> 6;
    const int ln15 = lane & 15;
    const int lq   = lane >> 4;
    const int b0   = blockIdx.x * 16;
    const int col  = 16 * w + ln15;

    h8 bh[3][4];
    float bhhF[3];
#pragma unroll
    for (int g = 0; g < 3; g++) {
        int n = g * H_ + col;
        bhhF[g] = bhh[n];
#pragma unroll
        for (int kt = 0; kt < 4; kt++) bh[g][kt] = load_w8(Whh + (size_t)n * H_ + kt * 32 + lq * 8);
    }
    // staging: 1536 b64-chunks (4 halfs) of the 16x384 step slab; 3 per thread
    int sRow[3], sC0[3];
    const _Float16* sgb[3];
#pragma unroll
    for (int k = 0; k < 3; k++) {
        int ch = tid + k * 512;
        sRow[k] = ch / 96;             // 96 chunks per row (384/4)
        sC0[k]  = (ch % 96) * 4;
        sgb[k]  = xw1 + (size_t)(b0 + sRow[k]) * T_ * G_ + sC0[k];
    }
    {   // zero h buf0
        _Float16* pa = &s_hA[0][0][0];
        for (int i = tid; i < 16 * 136; i += 512) pa[i] = (_Float16)0.f;
    }
    float2 pfA[3], pfB[3];
#pragma unroll
    for (int k = 0; k < 3; k++) {   // stage slot0 = xw(0); preload pfA = xw(1)
        float2 v = *(const float2*)(sgb[k]);
        *(float2*)&s_xw[0][sRow[k]][sC0[k]] = v;
        pfA[k] = *(const float2*)(sgb[k] + G_);
    }
    float hF[4] = {0.f, 0.f, 0.f, 0.f};
    __syncthreads();

    for (int t = 0; t < T_; t += 2) {
        // ---------------- even step t: consume slot0, h 0->1 ----------------
        {
            if (t + 2 < T_) {
#pragma unroll
                for (int k = 0; k < 3; k++) pfB[k] = *(const float2*)(sgb[k] + (size_t)(t + 2) * G_);
            }
            h8 ah[4];
#pragma unroll
            for (int kt = 0; kt < 4; kt++) ah[kt] = *(const h8*)&s_hA[0][ln15][kt * 32 + lq * 8];
            // write xw(t+1) (loaded last step / prologue) into slot1
#pragma unroll
            for (int k = 0; k < 3; k++) *(float2*)&s_xw[1][sRow[k]][sC0[k]] = pfA[k];
            f4 aH[3];
#pragma unroll
            for (int g = 0; g < 3; g++) aH[g] = (f4){bhhF[g], bhhF[g], bhhF[g], bhhF[g]};
#pragma unroll
            for (int kt = 0; kt < 4; kt++) {
                aH[0] = __builtin_amdgcn_mfma_f32_16x16x32_f16(ah[kt], bh[0][kt], aH[0], 0, 0, 0);
                aH[1] = __builtin_amdgcn_mfma_f32_16x16x32_f16(ah[kt], bh[1][kt], aH[1], 0, 0, 0);
                aH[2] = __builtin_amdgcn_mfma_f32_16x16x32_f16(ah[kt], bh[2][kt], aH[2], 0, 0, 0);
            }
#pragma unroll
            for (int reg = 0; reg < 4; reg++) {
                int brow = lq * 4 + reg;
                float r = sigm((float)s_xw[0][brow][col] + aH[0][reg]);
                float z = sigm((float)s_xw[0][brow][H_ + col] + aH[1][reg]);
                float n = tanh_f((float)s_xw[0][brow][2 * H_ + col] + r * aH[2][reg]);
                float h = n + z * (hF[reg] - n);
                hF[reg] = h;
                s_hA[1][brow][col] = (_Float16)h;
            }
            bar_lds();
        }
        // ---------------- odd step t+1: consume slot1, h 1->0 ----------------
        {
            if (t + 3 < T_) {
#pragma unroll
                for (int k = 0; k < 3; k++) pfA[k] = *(const float2*)(sgb[k] + (size_t)(t + 3) * G_);
            }
            h8 ah[4];
#pragma unroll
            for (int kt = 0; kt < 4; kt++) ah[kt] = *(const h8*)&s_hA[1][ln15][kt * 32 + lq * 8];
            if (t + 2 < T_) {
#pragma unroll
                for (int k = 0; k < 3; k++) *(float2*)&s_xw[0][sRow[k]][sC0[k]] = pfB[k];
            }
            f4 aH[3];
#pragma unroll
            for (int g = 0; g < 3; g++) aH[g] = (f4){bhhF[g], bhhF[g], bhhF[g], bhhF[g]};
#pragma unroll
            for (int kt = 0; kt < 4; kt++) {
                aH[0] = __builtin_amdgcn_mfma_f32_16x16x32_f16(ah[kt], bh[0][kt], aH[0], 0, 0, 0);
                aH[1] = __builtin_amdgcn_mfma_f32_16x16x32_f16(ah[kt], bh[1][kt], aH[1], 0, 0, 0);
                aH[2] = __builtin_amdgcn_mfma_f32_16x16x32_f16(ah[kt], bh[2][kt], aH[2], 0, 0, 0);
            }
#pragma unroll
            for (int reg = 0; reg < 4; reg++) {
                int brow = lq * 4 + reg;
                float r = sigm((float)s_xw[1][brow][col] + aH[0][reg]);
                float z = sigm((float)s_xw[1][brow][H_ + col] + aH[1][reg]);
                float n = tanh_f((float)s_xw[1][brow][2 * H_ + col] + r * aH[2][reg]);
                float h = n + z * (hF[reg] - n);
                hF[reg] = h;
                s_hA[0][brow][col] = (_Float16)h;
            }
            bar_lds();
        }
    }
#pragma unroll
    for (int reg = 0; reg < 4; reg++)
        h1f[(size_t)(b0 + lq * 4 + reg) * H_ + col] = hF[reg];
}

// ---------------- Tail: layer-1 bwd single step + relu + FC ----------------
__launch_bounds__(384)
__global__ void final_k(const _Float16* __restrict__ out0,
                        const float* __restrict__ h1f,
                        const __half2* __restrict__ w1b,   // packed Wih1b [128][384]
                        const float* __restrict__ bih1b, const float* __restrict__ bhh1b,
                        const float* __restrict__ fcw, const float* __restrict__ fcb,
                        float* __restrict__ out) {
    __shared__ __align__(16) float s_x1[HC];
    __shared__ __align__(16) float s_xw[G_];
    __shared__ __align__(16) float s_hc[HC];
    __shared__ float s_red[8];
    const int tid = threadIdx.x;
    const int b = blockIdx.x;
    if (tid < HC)
        s_x1[tid] = (float)out0[((size_t)b * T_ + (T_ - 1)) * HC + tid];
    __syncthreads();
    {
        float acc0 = 0.f, acc1 = 0.f;
        const float2* xv = (const float2*)s_x1;
#pragma unroll 8
        for (int k2 = 0; k2 < 128; k2 += 2) {
            float2 w0 = __half22float2(w1b[k2 * G_ + tid]);
            float2 w1 = __half22float2(w1b[(k2 + 1) * G_ + tid]);
            float2 a0 = xv[k2], a1 = xv[k2 + 1];
            acc0 += a0.x * w0.x + a0.y * w0.y;
            acc1 += a1.x * w1.x + a1.y * w1.y;
        }
        s_xw[tid] = bih1b[tid] + acc0 + acc1;
    }
    __syncthreads();
    if (tid < H_) {
        int j = tid;
        float rg = sigm(s_xw[j] + bhh1b[j]);
        float zg = sigm(s_xw[H_ + j] + bhh1b[H_ + j]);
        float ng = tanh_f(s_xw[2 * H_ + j] + rg * bhh1b[2 * H_ + j]);
        float hb = (1.f - zg) * ng;
        s_hc[H_ + j] = fmaxf(hb, 0.f);
        s_hc[j] = fmaxf(h1f[(size_t)b * H_ + j], 0.f);
    }
    __syncthreads();
    if (tid < HC) {
        float hv = s_hc[tid];
        float p0 = hv * fcw[tid];
        float p1 = hv * fcw[HC + tid];
#pragma unroll
        for (int off = 32; off; off >>= 1) {
            p0 += __shfl_down(p0, off);
            p1 += __shfl_down(p1, off);
        }
        if ((tid & 63) == 0) { s_red[(tid >> 6) * 2] = p0; s_red[(tid >> 6) * 2 + 1] = p1; }
    }
    __syncthreads();
    if (tid == 0) {
        out[b * 2 + 0] = fcb[0] + s_red[0] + s_red[2] + s_red[4] + s_red[6];
        out[b * 2 + 1] = fcb[1] + s_red[1] + s_red[3] + s_red[5] + s_red[7];
    }
}

extern "C" void kernel_launch(void* const* d_in, const int* in_sizes, int n_in,
                              void* d_out, int out_size, void* d_ws, size_t ws_size,
                              hipStream_t stream) {
    (void)in_sizes; (void)n_in; (void)out_size; (void)ws_size;
    const float* x     = (const float*)d_in[0];
    const float* Wih0f = (const float*)d_in[1];
    const float* Whh0f = (const float*)d_in[2];
    const float* bih0f = (const float*)d_in[3];
    const float* bhh0f = (const float*)d_in[4];
    const float* Wih0b = (const float*)d_in[5];
    const float* Whh0b = (const float*)d_in[6];
    const float* bih0b = (const float*)d_in[7];
    const float* bhh0b = (const float*)d_in[8];
    const float* Wih1f = (const float*)d_in[9];
    const float* Whh1f = (const float*)d_in[10];
    const float* bih1f = (const float*)d_in[11];
    const float* bhh1f = (const float*)d_in[12];
    const float* Wih1b = (const float*)d_in[13];
    const float* bih1b = (const float*)d_in[15];
    const float* bhh1b = (const float*)d_in[16];
    const float* fcw   = (const float*)d_in[17];
    const float* fcb   = (const float*)d_in[18];

    char* ws = (char*)d_ws;
    _Float16* out0 = (_Float16*)(ws + O_OUT0);
    _Float16* xw1  = (_Float16*)(ws + O_XW1);
    __half2*  wp   = (__half2*)(ws + O_WP);
    float*    h1f  = (float*)(ws + O_H1F);
    float*    out  = (float*)d_out;

    pack_wT<<<192, 256, 0, stream>>>(Wih1b, wp, 256, 49152);

    scan_l0<<<dim3(16, 2), 512, 0, stream>>>(x, Wih0f, Whh0f, bih0f, bhh0f,
                                             Wih0b, Whh0b, bih0b, bhh0b, out0);

    gemm_xw1<<<dim3(1024, 3), 256, 0, stream>>>(out0, Wih1f, bih1f, xw1);

    scan_l1<<<16, 512, 0, stream>>>(xw1, Whh1f, bhh1f, h1f);

    final_k<<<256, 384, 0, stream>>>(out0, h1f, wp, bih1b, bhh1b, fcw, fcb, out);
}

// Round 6
// 1010.311 us; speedup vs baseline: 3.2896x; 1.5049x over previous
//
#include <hip/hip_runtime.h>
#include <hip/hip_fp16.h>

#define B_  256
#define T_  512
#define I_  64
#define H_  128
#define G_  384
#define HC  256

// Workspace byte offsets (total ~168.1 MB)
#define O_OUT0 0ull                    // fp16 [B][T][2H] = 67,108,864
#define O_XW1  67108864ull             // fp16 [B][T][3H] (rows gate-permuted) = 100,663,296
#define O_WP   167772160ull            // packed half2 Wih1b, 196,608
#define O_H1F  (O_WP + 196608ull)      // f32 [B][H]

typedef _Float16 h8 __attribute__((ext_vector_type(8)));
typedef _Float16 h2 __attribute__((ext_vector_type(2)));
typedef float    f4 __attribute__((ext_vector_type(4)));

// v_rcp_f32 (~1ulp) instead of IEEE divide (~10 instr)
__device__ __forceinline__ float sigm(float x)   { return __builtin_amdgcn_rcpf(1.f + __expf(-x)); }
__device__ __forceinline__ float tanh_f(float x) { return 1.f - 2.f * __builtin_amdgcn_rcpf(1.f + __expf(2.f * x)); }

// LDS-only barrier: waits lgkmcnt(0) but NOT vmcnt — global stores (out0/h1f:
// no in-kernel reader) and in-flight prefetch loads cross freely.
__device__ __forceinline__ void bar_lds() {
    asm volatile("s_waitcnt lgkmcnt(0)\n\ts_barrier" ::: "memory");
}

__device__ __forceinline__ h8 load_w8(const float* src) {
    f4 a = *(const f4*)src;
    f4 b = *(const f4*)(src + 4);
    h8 v;
    v[0]=(_Float16)a[0]; v[1]=(_Float16)a[1]; v[2]=(_Float16)a[2]; v[3]=(_Float16)a[3];
    v[4]=(_Float16)b[0]; v[5]=(_Float16)b[1]; v[6]=(_Float16)b[2]; v[7]=(_Float16)b[3];
    return v;
}

// Transpose+pack a [384][K] fp32 weight into [K/2][384] half2 (for final_k).
__global__ void pack_wT(const float* __restrict__ W, __half2* __restrict__ dst,
                        int K, int total) {
    int i = blockIdx.x * 256 + threadIdx.x;
    if (i >= total) return;
    int c = i % G_;
    int k2 = i / G_;
    dst[i] = __halves2half2(__float2half(W[c * K + 2 * k2]),
                            __float2half(W[c * K + 2 * k2 + 1]));
}

// ---------------- Layer-0 scan ----------------
// 16 batch rows/block, dirs via blockIdx.y. 8 waves; wave w owns hidden units
// 16w..16w+15 with tiles (r,z,n): gate math + h-state in registers.
__launch_bounds__(512, 1)
__global__ void scan_l0(const float* __restrict__ x,
                        const float* __restrict__ Wih_f, const float* __restrict__ Whh_f,
                        const float* __restrict__ bih_f, const float* __restrict__ bhh_f,
                        const float* __restrict__ Wih_b, const float* __restrict__ Whh_b,
                        const float* __restrict__ bih_b, const float* __restrict__ bhh_b,
                        _Float16* __restrict__ out0) {
    __shared__ _Float16 s_hA[2][16][136];   // dbuf fp16 h (A-layout); 272B rows (16B-aligned)
    __shared__ _Float16 s_x[2][16][88];     // dbuf fp16 x(t); 176B rows (44 dw ≡ 12 mod 32)

    const int tid  = threadIdx.x;
    const int lane = tid & 63;
    const int w    = tid >> 6;          // wave 0..7
    const int ln15 = lane & 15;
    const int lq   = lane >> 4;         // 0..3
    const int dir  = blockIdx.y;
    const int b0   = blockIdx.x * 16;
    const int col  = 16 * w + ln15;     // hidden unit owned by this lane

    const float* Wih = dir ? Wih_b : Wih_f;
    const float* Whh = dir ? Whh_b : Whh_f;
    const float* bih = dir ? bih_b : bih_f;
    const float* bhh = dir ? bhh_b : bhh_f;

    // Register-resident B fragments, gate-permuted
    h8 bh[3][4], bx[3][2];
    float seedR, seedZ, bihN, bhhN;
    {
        seedR = bih[col] + bhh[col];
        seedZ = bih[H_ + col] + bhh[H_ + col];
        bihN  = bih[2 * H_ + col];
        bhhN  = bhh[2 * H_ + col];
#pragma unroll
        for (int g = 0; g < 3; g++) {
            int n = g * H_ + col;
#pragma unroll
            for (int kt = 0; kt < 4; kt++) bh[g][kt] = load_w8(Whh + (size_t)n * H_ + kt * 32 + lq * 8);
#pragma unroll
            for (int kt = 0; kt < 2; kt++) bx[g][kt] = load_w8(Wih + (size_t)n * I_ + kt * 32 + lq * 8);
        }
    }

    const int xr = tid >> 5, xc = (tid & 31) * 2;
    {   // zero h buf0, stage x(t=0) into buf0
        _Float16* pa = &s_hA[0][0][0];
        for (int i = tid; i < 16 * 136; i += 512) pa[i] = (_Float16)0.f;
        int tt0 = dir ? (T_ - 1) : 0;
        float2 xv = *(const float2*)(x + ((size_t)(b0 + xr) * T_ + tt0) * I_ + xc);
        s_x[0][xr][xc]     = (_Float16)xv.x;
        s_x[0][xr][xc + 1] = (_Float16)xv.y;
    }
    float hF[4] = {0.f, 0.f, 0.f, 0.f};
    __syncthreads();

    for (int t = 0; t < T_; ++t) {
        const int buf = t & 1;
        const int tt = dir ? (T_ - 1 - t) : t;
        // A fragments (h + x) from current buffer
        h8 ah[4], axf[2];
#pragma unroll
        for (int kt = 0; kt < 4; kt++) ah[kt] = *(const h8*)&s_hA[buf][ln15][kt * 32 + lq * 8];
#pragma unroll
        for (int kt = 0; kt < 2; kt++) axf[kt] = *(const h8*)&s_x[buf][ln15][kt * 32 + lq * 8];
        // prefetch x(t+1)
        float2 xpre;
        if (t < T_ - 1) {
            int tn = dir ? (tt - 1) : (tt + 1);
            xpre = *(const float2*)(x + ((size_t)(b0 + xr) * T_ + tn) * I_ + xc);
        }
        f4 aR  = (f4){seedR, seedR, seedR, seedR};
        f4 aZ  = (f4){seedZ, seedZ, seedZ, seedZ};
        f4 aXn = (f4){bihN, bihN, bihN, bihN};
        f4 aHn = (f4){bhhN, bhhN, bhhN, bhhN};
#pragma unroll
        for (int kt = 0; kt < 4; kt++) {
            aR  = __builtin_amdgcn_mfma_f32_16x16x32_f16(ah[kt], bh[0][kt], aR, 0, 0, 0);
            aZ  = __builtin_amdgcn_mfma_f32_16x16x32_f16(ah[kt], bh[1][kt], aZ, 0, 0, 0);
            aHn = __builtin_amdgcn_mfma_f32_16x16x32_f16(ah[kt], bh[2][kt], aHn, 0, 0, 0);
        }
#pragma unroll
        for (int kt = 0; kt < 2; kt++) {
            aR  = __builtin_amdgcn_mfma_f32_16x16x32_f16(axf[kt], bx[0][kt], aR, 0, 0, 0);
            aZ  = __builtin_amdgcn_mfma_f32_16x16x32_f16(axf[kt], bx[1][kt], aZ, 0, 0, 0);
            aXn = __builtin_amdgcn_mfma_f32_16x16x32_f16(axf[kt], bx[2][kt], aXn, 0, 0, 0);
        }
        // gates fully in registers (C layout: row=lq*4+reg, col=unit)
#pragma unroll
        for (int reg = 0; reg < 4; reg++) {
            float r = sigm(aR[reg]);
            float z = sigm(aZ[reg]);
            float n = tanh_f(aXn[reg] + r * aHn[reg]);
            float h = n + z * (hF[reg] - n);
            hF[reg] = h;
            int brow = lq * 4 + reg;
            out0[((size_t)(b0 + brow) * T_ + tt) * HC + dir * H_ + col] = (_Float16)h;
            s_hA[buf ^ 1][brow][col] = (_Float16)h;
        }
        if (t < T_ - 1) {
            s_x[buf ^ 1][xr][xc]     = (_Float16)xpre.x;
            s_x[buf ^ 1][xr][xc + 1] = (_Float16)xpre.y;
        }
        bar_lds();
    }
}

// ---------------- MFMA GEMM: xw1 = out0 @ Wih1f^T + bih1f ----------------
// Row layout of xw1 is gate-permuted: n<256 -> (n&127)*2 + (n>>7)  (r,z pairs),
// n>=256 -> n (n-gate region unchanged). scan_l1 consumes r+z as one b32.
__launch_bounds__(256)
__global__ void gemm_xw1(const _Float16* __restrict__ A,  // [M][256]
                         const float* __restrict__ Wf,    // [384][256]
                         const float* __restrict__ bias,
                         _Float16* __restrict__ C) {      // [M][384] permuted rows
    __shared__ _Float16 sA[128][40];
    __shared__ _Float16 sB[128][40];
    const int tid  = threadIdx.x;
    const int lane = tid & 63;
    const int w    = tid >> 6;
    const int wm   = w & 1, wn = w >> 1;
    const int ln15 = lane & 15, lq = lane >> 4;
    const size_t m0 = (size_t)blockIdx.x * 128;
    const int    n0 = blockIdx.y * 128;
    const int sr = tid >> 1, sc = (tid & 1) * 16;

    f4 acc[4][4] = {};

    for (int k0 = 0; k0 < 256; k0 += 32) {
        f4 av0 = *(const f4*)(A + (m0 + sr) * 256 + k0 + sc);
        f4 av1 = *(const f4*)(A + (m0 + sr) * 256 + k0 + sc + 8);
        const float* bsrc = Wf + (size_t)(n0 + sr) * 256 + k0 + sc;
        f4 b0v = *(const f4*)bsrc;
        f4 b1v = *(const f4*)(bsrc + 4);
        f4 b2v = *(const f4*)(bsrc + 8);
        f4 b3v = *(const f4*)(bsrc + 12);
        *(f4*)&sA[sr][sc]     = av0;
        *(f4*)&sA[sr][sc + 8] = av1;
        _Float16* bd = &sB[sr][sc];
        bd[0]=(_Float16)b0v[0]; bd[1]=(_Float16)b0v[1]; bd[2]=(_Float16)b0v[2]; bd[3]=(_Float16)b0v[3];
        bd[4]=(_Float16)b1v[0]; bd[5]=(_Float16)b1v[1]; bd[6]=(_Float16)b1v[2]; bd[7]=(_Float16)b1v[3];
        bd[8]=(_Float16)b2v[0]; bd[9]=(_Float16)b2v[1]; bd[10]=(_Float16)b2v[2]; bd[11]=(_Float16)b2v[3];
        bd[12]=(_Float16)b3v[0]; bd[13]=(_Float16)b3v[1]; bd[14]=(_Float16)b3v[2]; bd[15]=(_Float16)b3v[3];
        __syncthreads();
        h8 af[4], bf[4];
#pragma unroll
        for (int mt = 0; mt < 4; mt++) af[mt] = *(const h8*)&sA[wm * 64 + mt * 16 + ln15][lq * 8];
#pragma unroll
        for (int nt = 0; nt < 4; nt++) bf[nt] = *(const h8*)&sB[wn * 64 + nt * 16 + ln15][lq * 8];
#pragma unroll
        for (int mt = 0; mt < 4; mt++)
#pragma unroll
            for (int nt = 0; nt < 4; nt++)
                acc[mt][nt] = __builtin_amdgcn_mfma_f32_16x16x32_f16(af[mt], bf[nt], acc[mt][nt], 0, 0, 0);
        __syncthreads();
    }
#pragma unroll
    for (int nt = 0; nt < 4; nt++) {
        int col = n0 + wn * 64 + nt * 16 + ln15;
        float bb = bias[col];
        int pcol = (col < 256) ? ((col & 127) * 2 + (col >> 7)) : col;
#pragma unroll
        for (int mt = 0; mt < 4; mt++) {
            size_t row = m0 + wm * 64 + mt * 16 + lq * 4;
#pragma unroll
            for (int reg = 0; reg < 4; reg++)
                C[(row + reg) * G_ + pcol] = (_Float16)(acc[mt][nt][reg] + bb);
        }
    }
}

// ---------------- Layer-1 fwd scan: LDS ring (conflict-free layout) ----------------
// 512 threads, 16 blocks. Ring slot = unified region: rz rows pitch 268 halfs
// (quad stride 536 dw ≡ 24 mod 32 -> disjoint bank quarters), n rows pitch 140.
// xw consume: one b32 (r,z) + one u16 (n) per (row,unit).
#define RZP 268
#define NP  140
#define NB  (16 * RZP)                 // n-region base (halfs)
#define SLOT (NB + 16 * NP)            // 6528 halfs per slot
__launch_bounds__(512, 1)
__global__ void scan_l1(const _Float16* __restrict__ xw1,
                        const float* __restrict__ Whh,   // Whh1f [384][128]
                        const float* __restrict__ bhh,
                        float* __restrict__ h1f) {
    __shared__ _Float16 s_hA[2][16][136];
    __shared__ _Float16 s_ring[2][SLOT];

    const int tid  = threadIdx.x;
    const int lane = tid & 63;
    const int w    = tid >> 6;
    const int ln15 = lane & 15;
    const int lq   = lane >> 4;
    const int b0   = blockIdx.x * 16;
    const int col  = 16 * w + ln15;

    h8 bh[3][4];
    float bhhF[3];
#pragma unroll
    for (int g = 0; g < 3; g++) {
        int n = g * H_ + col;
        bhhF[g] = bhh[n];
#pragma unroll
        for (int kt = 0; kt < 4; kt++) bh[g][kt] = load_w8(Whh + (size_t)n * H_ + kt * 32 + lq * 8);
    }
    // staging: 1536 4-half chunks per step slab; 3 per thread; dst offset
    // computed once (c4<256 -> rz region, else n region).
    const _Float16* sgb[3];
    int dstoff[3];
#pragma unroll
    for (int k = 0; k < 3; k++) {
        int ch = tid + k * 512;
        int sRow = ch / 96;
        int c4 = (ch % 96) * 4;
        sgb[k] = xw1 + (size_t)(b0 + sRow) * T_ * G_ + c4;
        dstoff[k] = (c4 < 256) ? (sRow * RZP + c4) : (NB + sRow * NP + (c4 - 256));
    }
    {   // zero h buf0
        _Float16* pa = &s_hA[0][0][0];
        for (int i = tid; i < 16 * 136; i += 512) pa[i] = (_Float16)0.f;
    }
    float2 pfA[3], pfB[3];
#pragma unroll
    for (int k = 0; k < 3; k++) {   // stage slot0 = xw(0); preload pfA = xw(1)
        float2 v = *(const float2*)(sgb[k]);
        *(float2*)&s_ring[0][dstoff[k]] = v;
        pfA[k] = *(const float2*)(sgb[k] + G_);
    }
    float hF[4] = {0.f, 0.f, 0.f, 0.f};
    __syncthreads();

    for (int t = 0; t < T_; t += 2) {
        // ---------------- even step t: consume slot0, h 0->1 ----------------
        {
            if (t + 2 < T_) {
#pragma unroll
                for (int k = 0; k < 3; k++) pfB[k] = *(const float2*)(sgb[k] + (size_t)(t + 2) * G_);
            }
            h8 ah[4];
#pragma unroll
            for (int kt = 0; kt < 4; kt++) ah[kt] = *(const h8*)&s_hA[0][ln15][kt * 32 + lq * 8];
#pragma unroll
            for (int k = 0; k < 3; k++) *(float2*)&s_ring[1][dstoff[k]] = pfA[k];
            f4 aH[3];
#pragma unroll
            for (int g = 0; g < 3; g++) aH[g] = (f4){bhhF[g], bhhF[g], bhhF[g], bhhF[g]};
#pragma unroll
            for (int kt = 0; kt < 4; kt++) {
                aH[0] = __builtin_amdgcn_mfma_f32_16x16x32_f16(ah[kt], bh[0][kt], aH[0], 0, 0, 0);
                aH[1] = __builtin_amdgcn_mfma_f32_16x16x32_f16(ah[kt], bh[1][kt], aH[1], 0, 0, 0);
                aH[2] = __builtin_amdgcn_mfma_f32_16x16x32_f16(ah[kt], bh[2][kt], aH[2], 0, 0, 0);
            }
#pragma unroll
            for (int reg = 0; reg < 4; reg++) {
                int brow = lq * 4 + reg;
                h2 rz = *(const h2*)&s_ring[0][brow * RZP + col * 2];
                float xn = (float)s_ring[0][NB + brow * NP + col];
                float r = sigm((float)rz[0] + aH[0][reg]);
                float z = sigm((float)rz[1] + aH[1][reg]);
                float n = tanh_f(xn + r * aH[2][reg]);
                float h = n + z * (hF[reg] - n);
                hF[reg] = h;
                s_hA[1][brow][col] = (_Float16)h;
            }
            bar_lds();
        }
        // ---------------- odd step t+1: consume slot1, h 1->0 ----------------
        {
            if (t + 3 < T_) {
#pragma unroll
                for (int k = 0; k < 3; k++) pfA[k] = *(const float2*)(sgb[k] + (size_t)(t + 3) * G_);
            }
            h8 ah[4];
#pragma unroll
            for (int kt = 0; kt < 4; kt++) ah[kt] = *(const h8*)&s_hA[1][ln15][kt * 32 + lq * 8];
            if (t + 2 < T_) {
#pragma unroll
                for (int k = 0; k < 3; k++) *(float2*)&s_ring[0][dstoff[k]] = pfB[k];
            }
            f4 aH[3];
#pragma unroll
            for (int g = 0; g < 3; g++) aH[g] = (f4){bhhF[g], bhhF[g], bhhF[g], bhhF[g]};
#pragma unroll
            for (int kt = 0; kt < 4; kt++) {
                aH[0] = __builtin_amdgcn_mfma_f32_16x16x32_f16(ah[kt], bh[0][kt], aH[0], 0, 0, 0);
                aH[1] = __builtin_amdgcn_mfma_f32_16x16x32_f16(ah[kt], bh[1][kt], aH[1], 0, 0, 0);
                aH[2] = __builtin_amdgcn_mfma_f32_16x16x32_f16(ah[kt], bh[2][kt], aH[2], 0, 0, 0);
            }
#pragma unroll
            for (int reg = 0; reg < 4; reg++) {
                int brow = lq * 4 + reg;
                h2 rz = *(const h2*)&s_ring[1][brow * RZP + col * 2];
                float xn = (float)s_ring[1][NB + brow * NP + col];
                float r = sigm((float)rz[0] + aH[0][reg]);
                float z = sigm((float)rz[1] + aH[1][reg]);
                float n = tanh_f(xn + r * aH[2][reg]);
                float h = n + z * (hF[reg] - n);
                hF[reg] = h;
                s_hA[0][brow][col] = (_Float16)h;
            }
            bar_lds();
        }
    }
#pragma unroll
    for (int reg = 0; reg < 4; reg++)
        h1f[(size_t)(b0 + lq * 4 + reg) * H_ + col] = hF[reg];
}

// ---------------- Tail: layer-1 bwd single step + relu + FC ----------------
__launch_bounds__(384)
__global__ void final_k(const _Float16* __restrict__ out0,
                        const float* __restrict__ h1f,
                        const __half2* __restrict__ w1b,   // packed Wih1b [128][384]
                        const float* __restrict__ bih1b, const float* __restrict__ bhh1b,
                        const float* __restrict__ fcw, const float* __restrict__ fcb,
                        float* __restrict__ out) {
    __shared__ __align__(16) float s_x1[HC];
    __shared__ __align__(16) float s_xw[G_];
    __shared__ __align__(16) float s_hc[HC];
    __shared__ float s_red[8];
    const int tid = threadIdx.x;
    const int b = blockIdx.x;
    if (tid < HC)
        s_x1[tid] = (float)out0[((size_t)b * T_ + (T_ - 1)) * HC + tid];
    __syncthreads();
    {
        float acc0 = 0.f, acc1 = 0.f;
        const float2* xv = (const float2*)s_x1;
#pragma unroll 8
        for (int k2 = 0; k2 < 128; k2 += 2) {
            float2 w0 = __half22float2(w1b[k2 * G_ + tid]);
            float2 w1 = __half22float2(w1b[(k2 + 1) * G_ + tid]);
            float2 a0 = xv[k2], a1 = xv[k2 + 1];
            acc0 += a0.x * w0.x + a0.y * w0.y;
            acc1 += a1.x * w1.x + a1.y * w1.y;
        }
        s_xw[tid] = bih1b[tid] + acc0 + acc1;
    }
    __syncthreads();
    if (tid < H_) {
        int j = tid;
        float rg = sigm(s_xw[j] + bhh1b[j]);
        float zg = sigm(s_xw[H_ + j] + bhh1b[H_ + j]);
        float ng = tanh_f(s_xw[2 * H_ + j] + rg * bhh1b[2 * H_ + j]);
        float hb = (1.f - zg) * ng;
        s_hc[H_ + j] = fmaxf(hb, 0.f);
        s_hc[j] = fmaxf(h1f[(size_t)b * H_ + j], 0.f);
    }
    __syncthreads();
    if (tid < HC) {
        float hv = s_hc[tid];
        float p0 = hv * fcw[tid];
        float p1 = hv * fcw[HC + tid];
#pragma unroll
        for (int off = 32; off; off >>= 1) {
            p0 += __shfl_down(p0, off);
            p1 += __shfl_down(p1, off);
        }
        if ((tid & 63) == 0) { s_red[(tid >> 6) * 2] = p0; s_red[(tid >> 6) * 2 + 1] = p1; }
    }
    __syncthreads();
    if (tid == 0) {
        out[b * 2 + 0] = fcb[0] + s_red[0] + s_red[2] + s_red[4] + s_red[6];
        out[b * 2 + 1] = fcb[1] + s_red[1] + s_red[3] + s_red[5] + s_red[7];
    }
}

extern "C" void kernel_launch(void* const* d_in, const int* in_sizes, int n_in,
                              void* d_out, int out_size, void* d_ws, size_t ws_size,
                              hipStream_t stream) {
    (void)in_sizes; (void)n_in; (void)out_size; (void)ws_size;
    const float* x     = (const float*)d_in[0];
    const float* Wih0f = (const float*)d_in[1];
    const float* Whh0f = (const float*)d_in[2];
    const float* bih0f = (const float*)d_in[3];
    const float* bhh0f = (const float*)d_in[4];
    const float* Wih0b = (const float*)d_in[5];
    const float* Whh0b = (const float*)d_in[6];
    const float* bih0b = (const float*)d_in[7];
    const float* bhh0b = (const float*)d_in[8];
    const float* Wih1f = (const float*)d_in[9];
    const float* Whh1f = (const float*)d_in[10];
    const float* bih1f = (const float*)d_in[11];
    const float* bhh1f = (const float*)d_in[12];
    const float* Wih1b = (const float*)d_in[13];
    const float* bih1b = (const float*)d_in[15];
    const float* bhh1b = (const float*)d_in[16];
    const float* fcw   = (const float*)d_in[17];
    const float* fcb   = (const float*)d_in[18];

    char* ws = (char*)d_ws;
    _Float16* out0 = (_Float16*)(ws + O_OUT0);
    _Float16* xw1  = (_Float16*)(ws + O_XW1);
    __half2*  wp   = (__half2*)(ws + O_WP);
    float*    h1f  = (float*)(ws + O_H1F);
    float*    out  = (float*)d_out;

    pack_wT<<<192, 256, 0, stream>>>(Wih1b, wp, 256, 49152);

    scan_l0<<<dim3(16, 2), 512, 0, stream>>>(x, Wih0f, Whh0f, bih0f, bhh0f,
                                             Wih0b, Whh0b, bih0b, bhh0b, out0);

    gemm_xw1<<<dim3(1024, 3), 256, 0, stream>>>(out0, Wih1f, bih1f, xw1);

    scan_l1<<<16, 512, 0, stream>>>(xw1, Whh1f, bhh1f, h1f);

    final_k<<<256, 384, 0, stream>>>(out0, h1f, wp, bih1b, bhh1b, fcw, fcb, out);
}

// Round 7
// 850.952 us; speedup vs baseline: 3.9057x; 1.1873x over previous
//
#include <hip/hip_runtime.h>
#include <hip/hip_fp16.h>

#define B_  256
#define T_  512
#define I_  64
#define H_  128
#define G_  384
#define HC  256

// Workspace byte offsets (total ~168.1 MB)
#define O_OUT0 0ull                    // fp16 [B][T][2H] = 67,108,864
#define O_XW1  67108864ull             // fp16 [B][T][3H] (rows gate-permuted) = 100,663,296
#define O_WP   167772160ull            // packed half2 Wih1b, 196,608
#define O_H1F  (O_WP + 196608ull)      // f32 [B][H]

typedef _Float16 h8 __attribute__((ext_vector_type(8)));
typedef _Float16 h2 __attribute__((ext_vector_type(2)));
typedef float    f4 __attribute__((ext_vector_type(4)));

__device__ __forceinline__ float sigm(float x)   { return __builtin_amdgcn_rcpf(1.f + __expf(-x)); }
__device__ __forceinline__ float tanh_f(float x) { return 1.f - 2.f * __builtin_amdgcn_rcpf(1.f + __expf(2.f * x)); }

// LDS-only barrier: waits lgkmcnt(0) but NOT vmcnt.
__device__ __forceinline__ void bar_lds() {
    asm volatile("s_waitcnt lgkmcnt(0)\n\ts_barrier" ::: "memory");
}

__device__ __forceinline__ h8 load_w8(const float* src) {
    f4 a = *(const f4*)src;
    f4 b = *(const f4*)(src + 4);
    h8 v;
    v[0]=(_Float16)a[0]; v[1]=(_Float16)a[1]; v[2]=(_Float16)a[2]; v[3]=(_Float16)a[3];
    v[4]=(_Float16)b[0]; v[5]=(_Float16)b[1]; v[6]=(_Float16)b[2]; v[7]=(_Float16)b[3];
    return v;
}

// Transpose+pack a [384][K] fp32 weight into [K/2][384] half2 (for final_k).
__global__ void pack_wT(const float* __restrict__ W, __half2* __restrict__ dst,
                        int K, int total) {
    int i = blockIdx.x * 256 + threadIdx.x;
    if (i >= total) return;
    int c = i % G_;
    int k2 = i / G_;
    dst[i] = __halves2half2(__float2half(W[c * K + 2 * k2]),
                            __float2half(W[c * K + 2 * k2 + 1]));
}

// ---------------- Layer-0 scan: wave-specialized ----------------
// 768 threads: waves 0-7 compute (wave w owns units 16w..16w+15, gates in regs),
// waves 8-11 produce (x staging + coalesced out0 stores of prev step's h).
// s_h: 16x128 halfs, granule-XOR swizzle (g' = g ^ row) -> all b128 A-reads 2-way free.
__launch_bounds__(768, 1)
__global__ void scan_l0(const float* __restrict__ x,
                        const float* __restrict__ Wih_f, const float* __restrict__ Whh_f,
                        const float* __restrict__ bih_f, const float* __restrict__ bhh_f,
                        const float* __restrict__ Wih_b, const float* __restrict__ Whh_b,
                        const float* __restrict__ bih_b, const float* __restrict__ bhh_b,
                        _Float16* __restrict__ out0) {
    __shared__ __align__(16) _Float16 s_h[2][16 * 128];   // swizzled, 8 KB
    __shared__ __align__(16) _Float16 s_x[2][16 * 64];    // swizzled, 4 KB

    const int tid  = threadIdx.x;
    const int lane = tid & 63;
    const int w    = tid >> 6;          // 0..11
    const int dir  = blockIdx.y;
    const int b0   = blockIdx.x * 16;

    const float* Wih = dir ? Wih_b : Wih_f;
    const float* Whh = dir ? Whh_b : Whh_f;
    const float* bih = dir ? bih_b : bih_f;
    const float* bhh = dir ? bhh_b : bhh_f;

    {   // prologue: zero s_h[0]; producers stage x(tt(0)) into s_x[0]
        for (int i = tid; i < 16 * 128; i += 768) s_h[0][i] = (_Float16)0.f;
        if (w >= 8) {
            int pt = tid - 512;
            if (pt < 128) {
                int xr = pt >> 3, xg = pt & 7;
                int t0 = dir ? (T_ - 1) : 0;
                const float* src = x + ((size_t)(b0 + xr) * T_ + t0) * I_ + xg * 8;
                f4 a = *(const f4*)src, b = *(const f4*)(src + 4);
                h8 v;
                v[0]=(_Float16)a[0]; v[1]=(_Float16)a[1]; v[2]=(_Float16)a[2]; v[3]=(_Float16)a[3];
                v[4]=(_Float16)b[0]; v[5]=(_Float16)b[1]; v[6]=(_Float16)b[2]; v[7]=(_Float16)b[3];
                *(h8*)&s_x[0][xr * 64 + ((xg ^ (xr & 7)) & 7) * 8] = v;
            }
        }
    }
    __syncthreads();

    if (w < 8) {   // ================= COMPUTE =================
        const int ln15 = lane & 15;
        const int lq   = lane >> 4;
        const int col  = 16 * w + ln15;
        // B fragments (gate-permuted) in regs
        h8 bh[3][4], bx[3][2];
        float seedR = bih[col] + bhh[col];
        float seedZ = bih[H_ + col] + bhh[H_ + col];
        float bihN  = bih[2 * H_ + col];
        float bhhN  = bhh[2 * H_ + col];
#pragma unroll
        for (int g = 0; g < 3; g++) {
            int n = g * H_ + col;
#pragma unroll
            for (int kt = 0; kt < 4; kt++) bh[g][kt] = load_w8(Whh + (size_t)n * H_ + kt * 32 + lq * 8);
#pragma unroll
            for (int kt = 0; kt < 2; kt++) bx[g][kt] = load_w8(Wih + (size_t)n * I_ + kt * 32 + lq * 8);
        }
        // precomputed swizzled offsets (halfs)
        int offh[4], offx[2], offw[4];
#pragma unroll
        for (int kt = 0; kt < 4; kt++) offh[kt] = ln15 * 128 + (((kt * 4 + lq) ^ ln15) & 15) * 8;
#pragma unroll
        for (int kt = 0; kt < 2; kt++) offx[kt] = ln15 * 64 + (((kt * 4 + lq) ^ (ln15 & 7)) & 7) * 8;
#pragma unroll
        for (int reg = 0; reg < 4; reg++) {
            int row = lq * 4 + reg;
            offw[reg] = row * 128 + (((col >> 3) ^ row) & 15) * 8 + (col & 7);
        }
        float hF[4] = {0.f, 0.f, 0.f, 0.f};

#pragma unroll 1
        for (int t = 0; t < T_; t += 2) {
#pragma unroll
            for (int half_ = 0; half_ < 2; half_++) {   // slot = half_
                h8 ah[4], axf[2];
#pragma unroll
                for (int kt = 0; kt < 4; kt++) ah[kt] = *(const h8*)&s_h[half_][offh[kt]];
#pragma unroll
                for (int kt = 0; kt < 2; kt++) axf[kt] = *(const h8*)&s_x[half_][offx[kt]];
                f4 aR  = (f4){seedR, seedR, seedR, seedR};
                f4 aZ  = (f4){seedZ, seedZ, seedZ, seedZ};
                f4 aXn = (f4){bihN, bihN, bihN, bihN};
                f4 aHn = (f4){bhhN, bhhN, bhhN, bhhN};
#pragma unroll
                for (int kt = 0; kt < 4; kt++) {
                    aR  = __builtin_amdgcn_mfma_f32_16x16x32_f16(ah[kt], bh[0][kt], aR, 0, 0, 0);
                    aZ  = __builtin_amdgcn_mfma_f32_16x16x32_f16(ah[kt], bh[1][kt], aZ, 0, 0, 0);
                    aHn = __builtin_amdgcn_mfma_f32_16x16x32_f16(ah[kt], bh[2][kt], aHn, 0, 0, 0);
                }
#pragma unroll
                for (int kt = 0; kt < 2; kt++) {
                    aR  = __builtin_amdgcn_mfma_f32_16x16x32_f16(axf[kt], bx[0][kt], aR, 0, 0, 0);
                    aZ  = __builtin_amdgcn_mfma_f32_16x16x32_f16(axf[kt], bx[1][kt], aZ, 0, 0, 0);
                    aXn = __builtin_amdgcn_mfma_f32_16x16x32_f16(axf[kt], bx[2][kt], aXn, 0, 0, 0);
                }
#pragma unroll
                for (int reg = 0; reg < 4; reg++) {
                    float r = sigm(aR[reg]);
                    float z = sigm(aZ[reg]);
                    float n = tanh_f(aXn[reg] + r * aHn[reg]);
                    float h = n + z * (hF[reg] - n);
                    hF[reg] = h;
                    s_h[half_ ^ 1][offw[reg]] = (_Float16)h;
                }
                bar_lds();
            }
        }
    } else {       // ================= PRODUCER =================
        const int pt = tid - 512;            // 0..255
        const int r  = pt >> 4;
        const int c8 = (pt & 15) * 8;
        const int roff = r * 128 + (((c8 >> 3) ^ r) & 15) * 8;
        _Float16* obase = out0 + ((size_t)(b0 + r) * T_) * HC + dir * H_ + c8;
        const int xr = pt >> 3, xg = pt & 7;   // only pt<128 stage x
        const int xoff = xr * 64 + ((xg ^ (xr & 7)) & 7) * 8;
        const float* xbase = x + ((size_t)(b0 + xr) * T_) * I_ + xg * 8;

#pragma unroll 1
        for (int t = 0; t < T_; t += 2) {
#pragma unroll
            for (int half_ = 0; half_ < 2; half_++) {
                int s = t + half_;              // step index
                if (s > 0) {                    // store h(s) (in s_h[half_]) @ time tt(s-1)
                    int ttp = dir ? (T_ - s) : (s - 1);
                    f4 hv = *(const f4*)&s_h[half_][roff];
                    *(f4*)(obase + (size_t)ttp * HC) = hv;
                }
                if (pt < 128 && s + 1 < T_) {   // stage x for step s+1 @ time tt(s+1)
                    int tn = dir ? (T_ - 2 - s) : (s + 1);
                    const float* src = xbase + (size_t)tn * I_;
                    f4 a = *(const f4*)src, b = *(const f4*)(src + 4);
                    h8 v;
                    v[0]=(_Float16)a[0]; v[1]=(_Float16)a[1]; v[2]=(_Float16)a[2]; v[3]=(_Float16)a[3];
                    v[4]=(_Float16)b[0]; v[5]=(_Float16)b[1]; v[6]=(_Float16)b[2]; v[7]=(_Float16)b[3];
                    *(h8*)&s_x[half_ ^ 1][xoff] = v;
                }
                bar_lds();
            }
        }
        {   // epilogue: store h(T) (in s_h[0]) @ time tt(T-1)
            int ttp = dir ? 0 : (T_ - 1);
            f4 hv = *(const f4*)&s_h[0][roff];
            *(f4*)(obase + (size_t)ttp * HC) = hv;
        }
    }
}

// ---------------- MFMA GEMM: xw1 = out0 @ Wih1f^T + bih1f ----------------
// Row layout gate-permuted: n<256 -> (n&127)*2+(n>>7); n>=256 -> n.
__launch_bounds__(256)
__global__ void gemm_xw1(const _Float16* __restrict__ A,  // [M][256]
                         const float* __restrict__ Wf,    // [384][256]
                         const float* __restrict__ bias,
                         _Float16* __restrict__ C) {      // [M][384] permuted rows
    __shared__ _Float16 sA[128][40];
    __shared__ _Float16 sB[128][40];
    const int tid  = threadIdx.x;
    const int lane = tid & 63;
    const int w    = tid >> 6;
    const int wm   = w & 1, wn = w >> 1;
    const int ln15 = lane & 15, lq = lane >> 4;
    const size_t m0 = (size_t)blockIdx.x * 128;
    const int    n0 = blockIdx.y * 128;
    const int sr = tid >> 1, sc = (tid & 1) * 16;

    f4 acc[4][4] = {};

    for (int k0 = 0; k0 < 256; k0 += 32) {
        f4 av0 = *(const f4*)(A + (m0 + sr) * 256 + k0 + sc);
        f4 av1 = *(const f4*)(A + (m0 + sr) * 256 + k0 + sc + 8);
        const float* bsrc = Wf + (size_t)(n0 + sr) * 256 + k0 + sc;
        f4 b0v = *(const f4*)bsrc;
        f4 b1v = *(const f4*)(bsrc + 4);
        f4 b2v = *(const f4*)(bsrc + 8);
        f4 b3v = *(const f4*)(bsrc + 12);
        *(f4*)&sA[sr][sc]     = av0;
        *(f4*)&sA[sr][sc + 8] = av1;
        _Float16* bd = &sB[sr][sc];
        bd[0]=(_Float16)b0v[0]; bd[1]=(_Float16)b0v[1]; bd[2]=(_Float16)b0v[2]; bd[3]=(_Float16)b0v[3];
        bd[4]=(_Float16)b1v[0]; bd[5]=(_Float16)b1v[1]; bd[6]=(_Float16)b1v[2]; bd[7]=(_Float16)b1v[3];
        bd[8]=(_Float16)b2v[0]; bd[9]=(_Float16)b2v[1]; bd[10]=(_Float16)b2v[2]; bd[11]=(_Float16)b2v[3];
        bd[12]=(_Float16)b3v[0]; bd[13]=(_Float16)b3v[1]; bd[14]=(_Float16)b3v[2]; bd[15]=(_Float16)b3v[3];
        __syncthreads();
        h8 af[4], bf[4];
#pragma unroll
        for (int mt = 0; mt < 4; mt++) af[mt] = *(const h8*)&sA[wm * 64 + mt * 16 + ln15][lq * 8];
#pragma unroll
        for (int nt = 0; nt < 4; nt++) bf[nt] = *(const h8*)&sB[wn * 64 + nt * 16 + ln15][lq * 8];
#pragma unroll
        for (int mt = 0; mt < 4; mt++)
#pragma unroll
            for (int nt = 0; nt < 4; nt++)
                acc[mt][nt] = __builtin_amdgcn_mfma_f32_16x16x32_f16(af[mt], bf[nt], acc[mt][nt], 0, 0, 0);
        __syncthreads();
    }
#pragma unroll
    for (int nt = 0; nt < 4; nt++) {
        int col = n0 + wn * 64 + nt * 16 + ln15;
        float bb = bias[col];
        int pcol = (col < 256) ? ((col & 127) * 2 + (col >> 7)) : col;
#pragma unroll
        for (int mt = 0; mt < 4; mt++) {
            size_t row = m0 + wm * 64 + mt * 16 + lq * 4;
#pragma unroll
            for (int reg = 0; reg < 4; reg++)
                C[(row + reg) * G_ + pcol] = (_Float16)(acc[mt][nt][reg] + bb);
        }
    }
}

// ---------------- Layer-1 fwd scan: wave-specialized + ring ----------------
#define RZP 268
#define NP  140
#define NB  (16 * RZP)
#define SLOT (NB + 16 * NP)            // 6528 halfs per slot
__launch_bounds__(768, 1)
__global__ void scan_l1(const _Float16* __restrict__ xw1,
                        const float* __restrict__ Whh,   // Whh1f [384][128]
                        const float* __restrict__ bhh,
                        float* __restrict__ h1f) {
    __shared__ __align__(16) _Float16 s_h[2][16 * 128];
    __shared__ __align__(16) _Float16 s_ring[2][SLOT];

    const int tid  = threadIdx.x;
    const int lane = tid & 63;
    const int w    = tid >> 6;
    const int b0   = blockIdx.x * 16;

    {   // zero s_h[0]
        for (int i = tid; i < 16 * 128; i += 768) s_h[0][i] = (_Float16)0.f;
    }

    if (w < 8) {   // ================= COMPUTE =================
        const int ln15 = lane & 15;
        const int lq   = lane >> 4;
        const int col  = 16 * w + ln15;
        h8 bh[3][4];
        float bhhF[3];
#pragma unroll
        for (int g = 0; g < 3; g++) {
            int n = g * H_ + col;
            bhhF[g] = bhh[n];
#pragma unroll
            for (int kt = 0; kt < 4; kt++) bh[g][kt] = load_w8(Whh + (size_t)n * H_ + kt * 32 + lq * 8);
        }
        int offh[4], offw[4], offrz[4], offn[4];
#pragma unroll
        for (int kt = 0; kt < 4; kt++) offh[kt] = ln15 * 128 + (((kt * 4 + lq) ^ ln15) & 15) * 8;
#pragma unroll
        for (int reg = 0; reg < 4; reg++) {
            int row = lq * 4 + reg;
            offw[reg]  = row * 128 + (((col >> 3) ^ row) & 15) * 8 + (col & 7);
            offrz[reg] = row * RZP + col * 2;
            offn[reg]  = NB + row * NP + col;
        }
        float hF[4] = {0.f, 0.f, 0.f, 0.f};
        __syncthreads();

#pragma unroll 1
        for (int t = 0; t < T_; t += 2) {
#pragma unroll
            for (int half_ = 0; half_ < 2; half_++) {
                h8 ah[4];
#pragma unroll
                for (int kt = 0; kt < 4; kt++) ah[kt] = *(const h8*)&s_h[half_][offh[kt]];
                f4 aH[3];
#pragma unroll
                for (int g = 0; g < 3; g++) aH[g] = (f4){bhhF[g], bhhF[g], bhhF[g], bhhF[g]};
#pragma unroll
                for (int kt = 0; kt < 4; kt++) {
                    aH[0] = __builtin_amdgcn_mfma_f32_16x16x32_f16(ah[kt], bh[0][kt], aH[0], 0, 0, 0);
                    aH[1] = __builtin_amdgcn_mfma_f32_16x16x32_f16(ah[kt], bh[1][kt], aH[1], 0, 0, 0);
                    aH[2] = __builtin_amdgcn_mfma_f32_16x16x32_f16(ah[kt], bh[2][kt], aH[2], 0, 0, 0);
                }
#pragma unroll
                for (int reg = 0; reg < 4; reg++) {
                    h2 rz = *(const h2*)&s_ring[half_][offrz[reg]];
                    float xn = (float)s_ring[half_][offn[reg]];
                    float r = sigm((float)rz[0] + aH[0][reg]);
                    float z = sigm((float)rz[1] + aH[1][reg]);
                    float n = tanh_f(xn + r * aH[2][reg]);
                    float h = n + z * (hF[reg] - n);
                    hF[reg] = h;
                    s_h[half_ ^ 1][offw[reg]] = (_Float16)h;
                }
                bar_lds();
            }
        }
#pragma unroll
        for (int reg = 0; reg < 4; reg++)
            h1f[(size_t)(b0 + lq * 4 + reg) * H_ + col] = hF[reg];
    } else {       // ================= PRODUCER (ring staging) =================
        const int pt = tid - 512;            // 0..255, 6 chunks each
        const _Float16* sgb[6];
        int dstoff[6];
#pragma unroll
        for (int k = 0; k < 6; k++) {
            int ch = pt + k * 256;
            int sRow = ch / 96;
            int c4 = (ch % 96) * 4;
            sgb[k] = xw1 + (size_t)(b0 + sRow) * T_ * G_ + c4;
            dstoff[k] = (c4 < 256) ? (sRow * RZP + c4) : (NB + sRow * NP + (c4 - 256));
        }
        float2 pfA[6], pfB[6];
#pragma unroll
        for (int k = 0; k < 6; k++) {   // stage slot0 = xw(0); preload pfA = xw(1)
            float2 v = *(const float2*)(sgb[k]);
            *(float2*)&s_ring[0][dstoff[k]] = v;
            pfA[k] = *(const float2*)(sgb[k] + G_);
        }
        __syncthreads();

#pragma unroll 1
        for (int t = 0; t < T_; t += 2) {
            // even: write ring1 = xw(t+1); load xw(t+2)
            if (t + 2 < T_) {
#pragma unroll
                for (int k = 0; k < 6; k++) pfB[k] = *(const float2*)(sgb[k] + (size_t)(t + 2) * G_);
            }
#pragma unroll
            for (int k = 0; k < 6; k++) *(float2*)&s_ring[1][dstoff[k]] = pfA[k];
            bar_lds();
            // odd: write ring0 = xw(t+2); load xw(t+3)
            if (t + 3 < T_) {
#pragma unroll
                for (int k = 0; k < 6; k++) pfA[k] = *(const float2*)(sgb[k] + (size_t)(t + 3) * G_);
            }
            if (t + 2 < T_) {
#pragma unroll
                for (int k = 0; k < 6; k++) *(float2*)&s_ring[0][dstoff[k]] = pfB[k];
            }
            bar_lds();
        }
    }
}

// ---------------- Tail: layer-1 bwd single step + relu + FC ----------------
__launch_bounds__(384)
__global__ void final_k(const _Float16* __restrict__ out0,
                        const float* __restrict__ h1f,
                        const __half2* __restrict__ w1b,   // packed Wih1b [128][384]
                        const float* __restrict__ bih1b, const float* __restrict__ bhh1b,
                        const float* __restrict__ fcw, const float* __restrict__ fcb,
                        float* __restrict__ out) {
    __shared__ __align__(16) float s_x1[HC];
    __shared__ __align__(16) float s_xw[G_];
    __shared__ __align__(16) float s_hc[HC];
    __shared__ float s_red[8];
    const int tid = threadIdx.x;
    const int b = blockIdx.x;
    if (tid < HC)
        s_x1[tid] = (float)out0[((size_t)b * T_ + (T_ - 1)) * HC + tid];
    __syncthreads();
    {
        float acc0 = 0.f, acc1 = 0.f;
        const float2* xv = (const float2*)s_x1;
#pragma unroll 8
        for (int k2 = 0; k2 < 128; k2 += 2) {
            float2 w0 = __half22float2(w1b[k2 * G_ + tid]);
            float2 w1 = __half22float2(w1b[(k2 + 1) * G_ + tid]);
            float2 a0 = xv[k2], a1 = xv[k2 + 1];
            acc0 += a0.x * w0.x + a0.y * w0.y;
            acc1 += a1.x * w1.x + a1.y * w1.y;
        }
        s_xw[tid] = bih1b[tid] + acc0 + acc1;
    }
    __syncthreads();
    if (tid < H_) {
        int j = tid;
        float rg = sigm(s_xw[j] + bhh1b[j]);
        float zg = sigm(s_xw[H_ + j] + bhh1b[H_ + j]);
        float ng = tanh_f(s_xw[2 * H_ + j] + rg * bhh1b[2 * H_ + j]);
        float hb = (1.f - zg) * ng;
        s_hc[H_ + j] = fmaxf(hb, 0.f);
        s_hc[j] = fmaxf(h1f[(size_t)b * H_ + j], 0.f);
    }
    __syncthreads();
    if (tid < HC) {
        float hv = s_hc[tid];
        float p0 = hv * fcw[tid];
        float p1 = hv * fcw[HC + tid];
#pragma unroll
        for (int off = 32; off; off >>= 1) {
            p0 += __shfl_down(p0, off);
            p1 += __shfl_down(p1, off);
        }
        if ((tid & 63) == 0) { s_red[(tid >> 6) * 2] = p0; s_red[(tid >> 6) * 2 + 1] = p1; }
    }
    __syncthreads();
    if (tid == 0) {
        out[b * 2 + 0] = fcb[0] + s_red[0] + s_red[2] + s_red[4] + s_red[6];
        out[b * 2 + 1] = fcb[1] + s_red[1] + s_red[3] + s_red[5] + s_red[7];
    }
}

extern "C" void kernel_launch(void* const* d_in, const int* in_sizes, int n_in,
                              void* d_out, int out_size, void* d_ws, size_t ws_size,
                              hipStream_t stream) {
    (void)in_sizes; (void)n_in; (void)out_size; (void)ws_size;
    const float* x     = (const float*)d_in[0];
    const float* Wih0f = (const float*)d_in[1];
    const float* Whh0f = (const float*)d_in[2];
    const float* bih0f = (const float*)d_in[3];
    const float* bhh0f = (const float*)d_in[4];
    const float* Wih0b = (const float*)d_in[5];
    const float* Whh0b = (const float*)d_in[6];
    const float* bih0b = (const float*)d_in[7];
    const float* bhh0b = (const float*)d_in[8];
    const float* Wih1f = (const float*)d_in[9];
    const float* Whh1f = (const float*)d_in[10];
    const float* bih1f = (const float*)d_in[11];
    const float* bhh1f = (const float*)d_in[12];
    const float* Wih1b = (const float*)d_in[13];
    const float* bih1b = (const float*)d_in[15];
    const float* bhh1b = (const float*)d_in[16];
    const float* fcw   = (const float*)d_in[17];
    const float* fcb   = (const float*)d_in[18];

    char* ws = (char*)d_ws;
    _Float16* out0 = (_Float16*)(ws + O_OUT0);
    _Float16* xw1  = (_Float16*)(ws + O_XW1);
    __half2*  wp   = (__half2*)(ws + O_WP);
    float*    h1f  = (float*)(ws + O_H1F);
    float*    out  = (float*)d_out;

    pack_wT<<<192, 256, 0, stream>>>(Wih1b, wp, 256, 49152);

    scan_l0<<<dim3(16, 2), 768, 0, stream>>>(x, Wih0f, Whh0f, bih0f, bhh0f,
                                             Wih0b, Whh0b, bih0b, bhh0b, out0);

    gemm_xw1<<<dim3(1024, 3), 256, 0, stream>>>(out0, Wih1f, bih1f, xw1);

    scan_l1<<<16, 768, 0, stream>>>(xw1, Whh1f, bhh1f, h1f);

    final_k<<<256, 384, 0, stream>>>(out0, h1f, wp, bih1b, bhh1b, fcw, fcb, out);
}

// Round 8
// 835.362 us; speedup vs baseline: 3.9786x; 1.0187x over previous
//
#include <hip/hip_runtime.h>
#include <hip/hip_fp16.h>

#define B_  256
#define T_  512
#define I_  64
#define H_  128
#define G_  384
#define HC  256

// Workspace layout (stream-ordered aliasing: x16 occupies the head of the xw1
// region — gemm overwrites it only after scan_l0 has fully consumed x16).
#define O_OUT0 0ull                    // fp16 [B][T][2H] = 67,108,864
#define O_XW1  67108864ull             // fp16 [B][T][3H] = 100,663,296 (xw1; x16 aliases head)
#define O_X16  O_XW1                   // fp16 [B][T][64] = 16,777,216 (until gemm runs)
#define O_WP   167772160ull            // packed half2 Wih1b, 196,608
#define O_H1F  (O_WP + 196608ull)      // f32 [B][H] = 131,072
#define O_WF16 (O_H1F + 131072ull)     // fp16 Wih1f [384][256] = 196,608

typedef _Float16 h8 __attribute__((ext_vector_type(8)));
typedef _Float16 h2 __attribute__((ext_vector_type(2)));
typedef float    f4 __attribute__((ext_vector_type(4)));

__device__ __forceinline__ float sigm(float x)   { return __builtin_amdgcn_rcpf(1.f + __expf(-x)); }
__device__ __forceinline__ float tanh_f(float x) { return 1.f - 2.f * __builtin_amdgcn_rcpf(1.f + __expf(2.f * x)); }

// LDS-only barrier: waits lgkmcnt(0) but NOT vmcnt.
__device__ __forceinline__ void bar_lds() {
    asm volatile("s_waitcnt lgkmcnt(0)\n\ts_barrier" ::: "memory");
}

__device__ __forceinline__ h8 load_w8(const float* src) {
    f4 a = *(const f4*)src;
    f4 b = *(const f4*)(src + 4);
    h8 v;
    v[0]=(_Float16)a[0]; v[1]=(_Float16)a[1]; v[2]=(_Float16)a[2]; v[3]=(_Float16)a[3];
    v[4]=(_Float16)b[0]; v[5]=(_Float16)b[1]; v[6]=(_Float16)b[2]; v[7]=(_Float16)b[3];
    return v;
}

// fp32 -> fp16 bulk convert, 8 elems/thread.
__global__ void cvt16(const float* __restrict__ src, _Float16* __restrict__ dst, int n8) {
    int i = blockIdx.x * 256 + threadIdx.x;
    if (i >= n8) return;
    const float* s = src + (size_t)i * 8;
    f4 a = *(const f4*)s, b = *(const f4*)(s + 4);
    h8 v;
    v[0]=(_Float16)a[0]; v[1]=(_Float16)a[1]; v[2]=(_Float16)a[2]; v[3]=(_Float16)a[3];
    v[4]=(_Float16)b[0]; v[5]=(_Float16)b[1]; v[6]=(_Float16)b[2]; v[7]=(_Float16)b[3];
    *(h8*)(dst + (size_t)i * 8) = v;
}

// Transpose+pack a [384][K] fp32 weight into [K/2][384] half2 (for final_k).
__global__ void pack_wT(const float* __restrict__ W, __half2* __restrict__ dst,
                        int K, int total) {
    int i = blockIdx.x * 256 + threadIdx.x;
    if (i >= total) return;
    int c = i % G_;
    int k2 = i / G_;
    dst[i] = __halves2half2(__float2half(W[c * K + 2 * k2]),
                            __float2half(W[c * K + 2 * k2 + 1]));
}

// ---------------- Layer-0 scan: wave-specialized ----------------
// 768 threads: waves 0-7 compute, waves 8-11 produce (x16 b128 copy + coalesced
// out0 stores of prev step's h). XOR-swizzled s_h/s_x -> 0 bank conflicts.
__launch_bounds__(768, 1)
__global__ void scan_l0(const _Float16* __restrict__ x16,
                        const float* __restrict__ Wih_f, const float* __restrict__ Whh_f,
                        const float* __restrict__ bih_f, const float* __restrict__ bhh_f,
                        const float* __restrict__ Wih_b, const float* __restrict__ Whh_b,
                        const float* __restrict__ bih_b, const float* __restrict__ bhh_b,
                        _Float16* __restrict__ out0) {
    __shared__ __align__(16) _Float16 s_h[2][16 * 128];
    __shared__ __align__(16) _Float16 s_x[2][16 * 64];

    const int tid  = threadIdx.x;
    const int lane = tid & 63;
    const int w    = tid >> 6;
    const int dir  = blockIdx.y;
    const int b0   = blockIdx.x * 16;

    const float* Wih = dir ? Wih_b : Wih_f;
    const float* Whh = dir ? Whh_b : Whh_f;
    const float* bih = dir ? bih_b : bih_f;
    const float* bhh = dir ? bhh_b : bhh_f;

    {   // prologue: zero s_h[0]; producers stage x(tt(0)) into s_x[0]
        for (int i = tid; i < 16 * 128; i += 768) s_h[0][i] = (_Float16)0.f;
        if (w >= 8) {
            int pt = tid - 512;
            if (pt < 128) {
                int xr = pt >> 3, xg = pt & 7;
                int t0 = dir ? (T_ - 1) : 0;
                h8 v = *(const h8*)(x16 + ((size_t)(b0 + xr) * T_ + t0) * I_ + xg * 8);
                *(h8*)&s_x[0][xr * 64 + ((xg ^ (xr & 7)) & 7) * 8] = v;
            }
        }
    }
    __syncthreads();

    if (w < 8) {   // ================= COMPUTE =================
        const int ln15 = lane & 15;
        const int lq   = lane >> 4;
        const int col  = 16 * w + ln15;
        h8 bh[3][4], bx[3][2];
        float seedR = bih[col] + bhh[col];
        float seedZ = bih[H_ + col] + bhh[H_ + col];
        float bihN  = bih[2 * H_ + col];
        float bhhN  = bhh[2 * H_ + col];
#pragma unroll
        for (int g = 0; g < 3; g++) {
            int n = g * H_ + col;
#pragma unroll
            for (int kt = 0; kt < 4; kt++) bh[g][kt] = load_w8(Whh + (size_t)n * H_ + kt * 32 + lq * 8);
#pragma unroll
            for (int kt = 0; kt < 2; kt++) bx[g][kt] = load_w8(Wih + (size_t)n * I_ + kt * 32 + lq * 8);
        }
        int offh[4], offx[2], offw[4];
#pragma unroll
        for (int kt = 0; kt < 4; kt++) offh[kt] = ln15 * 128 + (((kt * 4 + lq) ^ ln15) & 15) * 8;
#pragma unroll
        for (int kt = 0; kt < 2; kt++) offx[kt] = ln15 * 64 + (((kt * 4 + lq) ^ (ln15 & 7)) & 7) * 8;
#pragma unroll
        for (int reg = 0; reg < 4; reg++) {
            int row = lq * 4 + reg;
            offw[reg] = row * 128 + (((col >> 3) ^ row) & 15) * 8 + (col & 7);
        }
        float hF[4] = {0.f, 0.f, 0.f, 0.f};

#pragma unroll 1
        for (int t = 0; t < T_; t += 2) {
#pragma unroll
            for (int half_ = 0; half_ < 2; half_++) {
                h8 ah[4], axf[2];
#pragma unroll
                for (int kt = 0; kt < 4; kt++) ah[kt] = *(const h8*)&s_h[half_][offh[kt]];
#pragma unroll
                for (int kt = 0; kt < 2; kt++) axf[kt] = *(const h8*)&s_x[half_][offx[kt]];
                f4 aR  = (f4){seedR, seedR, seedR, seedR};
                f4 aZ  = (f4){seedZ, seedZ, seedZ, seedZ};
                f4 aXn = (f4){bihN, bihN, bihN, bihN};
                f4 aHn = (f4){bhhN, bhhN, bhhN, bhhN};
#pragma unroll
                for (int kt = 0; kt < 4; kt++) {
                    aR  = __builtin_amdgcn_mfma_f32_16x16x32_f16(ah[kt], bh[0][kt], aR, 0, 0, 0);
                    aZ  = __builtin_amdgcn_mfma_f32_16x16x32_f16(ah[kt], bh[1][kt], aZ, 0, 0, 0);
                    aHn = __builtin_amdgcn_mfma_f32_16x16x32_f16(ah[kt], bh[2][kt], aHn, 0, 0, 0);
                }
#pragma unroll
                for (int kt = 0; kt < 2; kt++) {
                    aR  = __builtin_amdgcn_mfma_f32_16x16x32_f16(axf[kt], bx[0][kt], aR, 0, 0, 0);
                    aZ  = __builtin_amdgcn_mfma_f32_16x16x32_f16(axf[kt], bx[1][kt], aZ, 0, 0, 0);
                    aXn = __builtin_amdgcn_mfma_f32_16x16x32_f16(axf[kt], bx[2][kt], aXn, 0, 0, 0);
                }
#pragma unroll
                for (int reg = 0; reg < 4; reg++) {
                    float r = sigm(aR[reg]);
                    float z = sigm(aZ[reg]);
                    float n = tanh_f(aXn[reg] + r * aHn[reg]);
                    float h = n + z * (hF[reg] - n);
                    hF[reg] = h;
                    s_h[half_ ^ 1][offw[reg]] = (_Float16)h;
                }
                bar_lds();
            }
        }
    } else {       // ================= PRODUCER =================
        const int pt = tid - 512;
        const int r  = pt >> 4;
        const int c8 = (pt & 15) * 8;
        const int roff = r * 128 + (((c8 >> 3) ^ r) & 15) * 8;
        _Float16* obase = out0 + ((size_t)(b0 + r) * T_) * HC + dir * H_ + c8;
        const int xr = pt >> 3, xg = pt & 7;
        const int xoff = xr * 64 + ((xg ^ (xr & 7)) & 7) * 8;
        const _Float16* xbase = x16 + ((size_t)(b0 + xr) * T_) * I_ + xg * 8;

#pragma unroll 1
        for (int t = 0; t < T_; t += 2) {
#pragma unroll
            for (int half_ = 0; half_ < 2; half_++) {
                int s = t + half_;
                if (s > 0) {
                    int ttp = dir ? (T_ - s) : (s - 1);
                    f4 hv = *(const f4*)&s_h[half_][roff];
                    *(f4*)(obase + (size_t)ttp * HC) = hv;
                }
                if (pt < 128 && s + 1 < T_) {
                    int tn = dir ? (T_ - 2 - s) : (s + 1);
                    h8 v = *(const h8*)(xbase + (size_t)tn * I_);
                    *(h8*)&s_x[half_ ^ 1][xoff] = v;
                }
                bar_lds();
            }
        }
        {
            int ttp = dir ? 0 : (T_ - 1);
            f4 hv = *(const f4*)&s_h[0][roff];
            *(f4*)(obase + (size_t)ttp * HC) = hv;
        }
    }
}

// ---------------- MFMA GEMM v2: xw1 = out0 @ Wih1f^T + bih1f ----------------
// fp16 A and B, BK=64 (4 chunks), XOR-swizzled LDS, grid (3 N-fast, 1024 M)
// so the 3 N-blocks of one M-tile share the A-tile in L2.
// Output rows gate-permuted: n<256 -> (n&127)*2+(n>>7); n>=256 -> n.
__launch_bounds__(256, 2)
__global__ void gemm_xw1(const _Float16* __restrict__ A,   // [M][256]
                         const _Float16* __restrict__ Bw,  // [384][256] fp16
                         const float* __restrict__ bias,
                         _Float16* __restrict__ C) {       // [M][384] permuted rows
    __shared__ __align__(16) _Float16 sA[128 * 64];
    __shared__ __align__(16) _Float16 sB[128 * 64];
    const int tid  = threadIdx.x;
    const int lane = tid & 63;
    const int w    = tid >> 6;
    const int wm   = w & 1, wn = w >> 1;
    const int ln15 = lane & 15, lq = lane >> 4;
    const int    n0 = blockIdx.x * 128;
    const size_t m0 = (size_t)blockIdx.y * 128;

    f4 acc[4][4] = {};

    // staging map: 4 h8-granules per thread per chunk
    int sRow[4], sG[4], sOff[4];
#pragma unroll
    for (int k = 0; k < 4; k++) {
        int idx = k * 256 + tid;
        sRow[k] = idx >> 3;
        sG[k]   = idx & 7;
        sOff[k] = sRow[k] * 64 + ((sG[k] ^ (sRow[k] & 7)) & 7) * 8;
    }
    // frag read offsets
    int offA[4][2], offB[4][2];
#pragma unroll
    for (int mt = 0; mt < 4; mt++)
#pragma unroll
        for (int kt = 0; kt < 2; kt++) {
            int rowA = wm * 64 + mt * 16 + ln15;
            offA[mt][kt] = rowA * 64 + (((kt * 4 + lq) ^ (rowA & 7)) & 7) * 8;
            int rowB = wn * 64 + mt * 16 + ln15;
            offB[mt][kt] = rowB * 64 + (((kt * 4 + lq) ^ (rowB & 7)) & 7) * 8;
        }

    for (int k0 = 0; k0 < 256; k0 += 64) {
#pragma unroll
        for (int k = 0; k < 4; k++) {
            h8 av = *(const h8*)(A + (m0 + sRow[k]) * 256 + k0 + sG[k] * 8);
            h8 bv = *(const h8*)(Bw + (size_t)(n0 + sRow[k]) * 256 + k0 + sG[k] * 8);
            *(h8*)&sA[sOff[k]] = av;
            *(h8*)&sB[sOff[k]] = bv;
        }
        __syncthreads();
#pragma unroll
        for (int kt = 0; kt < 2; kt++) {
            h8 af[4], bf[4];
#pragma unroll
            for (int mt = 0; mt < 4; mt++) af[mt] = *(const h8*)&sA[offA[mt][kt]];
#pragma unroll
            for (int nt = 0; nt < 4; nt++) bf[nt] = *(const h8*)&sB[offB[nt][kt]];
#pragma unroll
            for (int mt = 0; mt < 4; mt++)
#pragma unroll
                for (int nt = 0; nt < 4; nt++)
                    acc[mt][nt] = __builtin_amdgcn_mfma_f32_16x16x32_f16(af[mt], bf[nt], acc[mt][nt], 0, 0, 0);
        }
        __syncthreads();
    }
#pragma unroll
    for (int nt = 0; nt < 4; nt++) {
        int col = n0 + wn * 64 + nt * 16 + ln15;
        float bb = bias[col];
        int pcol = (col < 256) ? ((col & 127) * 2 + (col >> 7)) : col;
#pragma unroll
        for (int mt = 0; mt < 4; mt++) {
            size_t row = m0 + wm * 64 + mt * 16 + lq * 4;
#pragma unroll
            for (int reg = 0; reg < 4; reg++)
                C[(row + reg) * G_ + pcol] = (_Float16)(acc[mt][nt][reg] + bb);
        }
    }
}

// ---------------- Layer-1 fwd scan: wave-specialized + ring ----------------
#define RZP 268
#define NP  140
#define NB  (16 * RZP)
#define SLOT (NB + 16 * NP)
__launch_bounds__(768, 1)
__global__ void scan_l1(const _Float16* __restrict__ xw1,
                        const float* __restrict__ Whh,
                        const float* __restrict__ bhh,
                        float* __restrict__ h1f) {
    __shared__ __align__(16) _Float16 s_h[2][16 * 128];
    __shared__ __align__(16) _Float16 s_ring[2][SLOT];

    const int tid  = threadIdx.x;
    const int lane = tid & 63;
    const int w    = tid >> 6;
    const int b0   = blockIdx.x * 16;

    {
        for (int i = tid; i < 16 * 128; i += 768) s_h[0][i] = (_Float16)0.f;
    }

    if (w < 8) {   // ================= COMPUTE =================
        const int ln15 = lane & 15;
        const int lq   = lane >> 4;
        const int col  = 16 * w + ln15;
        h8 bh[3][4];
        float bhhF[3];
#pragma unroll
        for (int g = 0; g < 3; g++) {
            int n = g * H_ + col;
            bhhF[g] = bhh[n];
#pragma unroll
            for (int kt = 0; kt < 4; kt++) bh[g][kt] = load_w8(Whh + (size_t)n * H_ + kt * 32 + lq * 8);
        }
        int offh[4], offw[4], offrz[4], offn[4];
#pragma unroll
        for (int kt = 0; kt < 4; kt++) offh[kt] = ln15 * 128 + (((kt * 4 + lq) ^ ln15) & 15) * 8;
#pragma unroll
        for (int reg = 0; reg < 4; reg++) {
            int row = lq * 4 + reg;
            offw[reg]  = row * 128 + (((col >> 3) ^ row) & 15) * 8 + (col & 7);
            offrz[reg] = row * RZP + col * 2;
            offn[reg]  = NB + row * NP + col;
        }
        float hF[4] = {0.f, 0.f, 0.f, 0.f};
        __syncthreads();

#pragma unroll 1
        for (int t = 0; t < T_; t += 2) {
#pragma unroll
            for (int half_ = 0; half_ < 2; half_++) {
                h8 ah[4];
#pragma unroll
                for (int kt = 0; kt < 4; kt++) ah[kt] = *(const h8*)&s_h[half_][offh[kt]];
                f4 aH[3];
#pragma unroll
                for (int g = 0; g < 3; g++) aH[g] = (f4){bhhF[g], bhhF[g], bhhF[g], bhhF[g]};
#pragma unroll
                for (int kt = 0; kt < 4; kt++) {
                    aH[0] = __builtin_amdgcn_mfma_f32_16x16x32_f16(ah[kt], bh[0][kt], aH[0], 0, 0, 0);
                    aH[1] = __builtin_amdgcn_mfma_f32_16x16x32_f16(ah[kt], bh[1][kt], aH[1], 0, 0, 0);
                    aH[2] = __builtin_amdgcn_mfma_f32_16x16x32_f16(ah[kt], bh[2][kt], aH[2], 0, 0, 0);
                }
#pragma unroll
                for (int reg = 0; reg < 4; reg++) {
                    h2 rz = *(const h2*)&s_ring[half_][offrz[reg]];
                    float xn = (float)s_ring[half_][offn[reg]];
                    float r = sigm((float)rz[0] + aH[0][reg]);
                    float z = sigm((float)rz[1] + aH[1][reg]);
                    float n = tanh_f(xn + r * aH[2][reg]);
                    float h = n + z * (hF[reg] - n);
                    hF[reg] = h;
                    s_h[half_ ^ 1][offw[reg]] = (_Float16)h;
                }
                bar_lds();
            }
        }
#pragma unroll
        for (int reg = 0; reg < 4; reg++)
            h1f[(size_t)(b0 + lq * 4 + reg) * H_ + col] = hF[reg];
    } else {       // ================= PRODUCER (ring staging) =================
        const int pt = tid - 512;
        const _Float16* sgb[6];
        int dstoff[6];
#pragma unroll
        for (int k = 0; k < 6; k++) {
            int ch = pt + k * 256;
            int sRow = ch / 96;
            int c4 = (ch % 96) * 4;
            sgb[k] = xw1 + (size_t)(b0 + sRow) * T_ * G_ + c4;
            dstoff[k] = (c4 < 256) ? (sRow * RZP + c4) : (NB + sRow * NP + (c4 - 256));
        }
        float2 pfA[6], pfB[6];
#pragma unroll
        for (int k = 0; k < 6; k++) {
            float2 v = *(const float2*)(sgb[k]);
            *(float2*)&s_ring[0][dstoff[k]] = v;
            pfA[k] = *(const float2*)(sgb[k] + G_);
        }
        __syncthreads();

#pragma unroll 1
        for (int t = 0; t < T_; t += 2) {
            if (t + 2 < T_) {
#pragma unroll
                for (int k = 0; k < 6; k++) pfB[k] = *(const float2*)(sgb[k] + (size_t)(t + 2) * G_);
            }
#pragma unroll
            for (int k = 0; k < 6; k++) *(float2*)&s_ring[1][dstoff[k]] = pfA[k];
            bar_lds();
            if (t + 3 < T_) {
#pragma unroll
                for (int k = 0; k < 6; k++) pfA[k] = *(const float2*)(sgb[k] + (size_t)(t + 3) * G_);
            }
            if (t + 2 < T_) {
#pragma unroll
                for (int k = 0; k < 6; k++) *(float2*)&s_ring[0][dstoff[k]] = pfB[k];
            }
            bar_lds();
        }
    }
}

// ---------------- Tail: layer-1 bwd single step + relu + FC ----------------
__launch_bounds__(384)
__global__ void final_k(const _Float16* __restrict__ out0,
                        const float* __restrict__ h1f,
                        const __half2* __restrict__ w1b,
                        const float* __restrict__ bih1b, const float* __restrict__ bhh1b,
                        const float* __restrict__ fcw, const float* __restrict__ fcb,
                        float* __restrict__ out) {
    __shared__ __align__(16) float s_x1[HC];
    __shared__ __align__(16) float s_xw[G_];
    __shared__ __align__(16) float s_hc[HC];
    __shared__ float s_red[8];
    const int tid = threadIdx.x;
    const int b = blockIdx.x;
    if (tid < HC)
        s_x1[tid] = (float)out0[((size_t)b * T_ + (T_ - 1)) * HC + tid];
    __syncthreads();
    {
        float acc0 = 0.f, acc1 = 0.f;
        const float2* xv = (const float2*)s_x1;
#pragma unroll 8
        for (int k2 = 0; k2 < 128; k2 += 2) {
            float2 w0 = __half22float2(w1b[k2 * G_ + tid]);
            float2 w1 = __half22float2(w1b[(k2 + 1) * G_ + tid]);
            float2 a0 = xv[k2], a1 = xv[k2 + 1];
            acc0 += a0.x * w0.x + a0.y * w0.y;
            acc1 += a1.x * w1.x + a1.y * w1.y;
        }
        s_xw[tid] = bih1b[tid] + acc0 + acc1;
    }
    __syncthreads();
    if (tid < H_) {
        int j = tid;
        float rg = sigm(s_xw[j] + bhh1b[j]);
        float zg = sigm(s_xw[H_ + j] + bhh1b[H_ + j]);
        float ng = tanh_f(s_xw[2 * H_ + j] + rg * bhh1b[2 * H_ + j]);
        float hb = (1.f - zg) * ng;
        s_hc[H_ + j] = fmaxf(hb, 0.f);
        s_hc[j] = fmaxf(h1f[(size_t)b * H_ + j], 0.f);
    }
    __syncthreads();
    if (tid < HC) {
        float hv = s_hc[tid];
        float p0 = hv * fcw[tid];
        float p1 = hv * fcw[HC + tid];
#pragma unroll
        for (int off = 32; off; off >>= 1) {
            p0 += __shfl_down(p0, off);
            p1 += __shfl_down(p1, off);
        }
        if ((tid & 63) == 0) { s_red[(tid >> 6) * 2] = p0; s_red[(tid >> 6) * 2 + 1] = p1; }
    }
    __syncthreads();
    if (tid == 0) {
        out[b * 2 + 0] = fcb[0] + s_red[0] + s_red[2] + s_red[4] + s_red[6];
        out[b * 2 + 1] = fcb[1] + s_red[1] + s_red[3] + s_red[5] + s_red[7];
    }
}

extern "C" void kernel_launch(void* const* d_in, const int* in_sizes, int n_in,
                              void* d_out, int out_size, void* d_ws, size_t ws_size,
                              hipStream_t stream) {
    (void)in_sizes; (void)n_in; (void)out_size; (void)ws_size;
    const float* x     = (const float*)d_in[0];
    const float* Wih0f = (const float*)d_in[1];
    const float* Whh0f = (const float*)d_in[2];
    const float* bih0f = (const float*)d_in[3];
    const float* bhh0f = (const float*)d_in[4];
    const float* Wih0b = (const float*)d_in[5];
    const float* Whh0b = (const float*)d_in[6];
    const float* bih0b = (const float*)d_in[7];
    const float* bhh0b = (const float*)d_in[8];
    const float* Wih1f = (const float*)d_in[9];
    const float* Whh1f = (const float*)d_in[10];
    const float* bih1f = (const float*)d_in[11];
    const float* bhh1f = (const float*)d_in[12];
    const float* Wih1b = (const float*)d_in[13];
    const float* bih1b = (const float*)d_in[15];
    const float* bhh1b = (const float*)d_in[16];
    const float* fcw   = (const float*)d_in[17];
    const float* fcb   = (const float*)d_in[18];

    char* ws = (char*)d_ws;
    _Float16* out0 = (_Float16*)(ws + O_OUT0);
    _Float16* xw1  = (_Float16*)(ws + O_XW1);
    _Float16* x16  = (_Float16*)(ws + O_X16);
    __half2*  wp   = (__half2*)(ws + O_WP);
    float*    h1f  = (float*)(ws + O_H1F);
    _Float16* wf16 = (_Float16*)(ws + O_WF16);
    float*    out  = (float*)d_out;

    // prep: x->fp16 (aliased on xw1 head), Wih1f->fp16, Wih1b packed
    cvt16<<<4096, 256, 0, stream>>>(x, x16, 1048576);
    cvt16<<<48, 256, 0, stream>>>(Wih1f, wf16, 12288);
    pack_wT<<<192, 256, 0, stream>>>(Wih1b, wp, 256, 49152);

    scan_l0<<<dim3(16, 2), 768, 0, stream>>>(x16, Wih0f, Whh0f, bih0f, bhh0f,
                                             Wih0b, Whh0b, bih0b, bhh0b, out0);

    gemm_xw1<<<dim3(3, 1024), 256, 0, stream>>>(out0, wf16, bih1f, xw1);

    scan_l1<<<16, 768, 0, stream>>>(xw1, Whh1f, bhh1f, h1f);

    final_k<<<256, 384, 0, stream>>>(out0, h1f, wp, bih1b, bhh1b, fcw, fcb, out);
}

// Round 9
// 822.975 us; speedup vs baseline: 4.0384x; 1.0151x over previous
//
#include <hip/hip_runtime.h>
#include <hip/hip_fp16.h>

#define B_  256
#define T_  512
#define I_  64
#define H_  128
#define G_  384
#define HC  256

// Workspace layout (stream-ordered aliasing: x16 occupies the head of the xw1
// region — gemm overwrites it only after scan_l0 has fully consumed x16).
#define O_OUT0 0ull                    // fp16 [B][T][2H] = 67,108,864
#define O_XW1  67108864ull             // fp16 [B][T][3H] = 100,663,296 (xw1; x16 aliases head)
#define O_X16  O_XW1                   // fp16 [B][T][64] = 16,777,216 (until gemm runs)
#define O_WP   167772160ull            // packed half2 Wih1b, 196,608
#define O_H1F  (O_WP + 196608ull)      // f32 [B][H] = 131,072
#define O_WF16 (O_H1F + 131072ull)     // fp16 Wih1f [384][256] = 196,608

typedef _Float16 h8 __attribute__((ext_vector_type(8)));
typedef _Float16 h2 __attribute__((ext_vector_type(2)));
typedef float    f4 __attribute__((ext_vector_type(4)));

__device__ __forceinline__ float sigm(float x)   { return __builtin_amdgcn_rcpf(1.f + __expf(-x)); }
__device__ __forceinline__ float tanh_f(float x) { return 1.f - 2.f * __builtin_amdgcn_rcpf(1.f + __expf(2.f * x)); }

// LDS-only barrier: waits lgkmcnt(0) but NOT vmcnt.
__device__ __forceinline__ void bar_lds() {
    asm volatile("s_waitcnt lgkmcnt(0)\n\ts_barrier" ::: "memory");
}

__device__ __forceinline__ h8 load_w8(const float* src) {
    f4 a = *(const f4*)src;
    f4 b = *(const f4*)(src + 4);
    h8 v;
    v[0]=(_Float16)a[0]; v[1]=(_Float16)a[1]; v[2]=(_Float16)a[2]; v[3]=(_Float16)a[3];
    v[4]=(_Float16)b[0]; v[5]=(_Float16)b[1]; v[6]=(_Float16)b[2]; v[7]=(_Float16)b[3];
    return v;
}

// Fused prep: x->fp16 (4096 blocks), Wih1f->fp16 (48), Wih1b pack-T (192).
__global__ void prep(const float* __restrict__ x, _Float16* __restrict__ x16,
                     const float* __restrict__ Wf, _Float16* __restrict__ wf16,
                     const float* __restrict__ W1b, __half2* __restrict__ wp) {
    const int bid = blockIdx.x;
    const int tid = threadIdx.x;
    if (bid < 4096) {          // x: 1,048,576 groups of 8
        int i = bid * 256 + tid;
        const float* s = x + (size_t)i * 8;
        f4 a = *(const f4*)s, b = *(const f4*)(s + 4);
        h8 v;
        v[0]=(_Float16)a[0]; v[1]=(_Float16)a[1]; v[2]=(_Float16)a[2]; v[3]=(_Float16)a[3];
        v[4]=(_Float16)b[0]; v[5]=(_Float16)b[1]; v[6]=(_Float16)b[2]; v[7]=(_Float16)b[3];
        *(h8*)(x16 + (size_t)i * 8) = v;
    } else if (bid < 4144) {   // Wih1f: 12,288 groups of 8
        int i = (bid - 4096) * 256 + tid;
        const float* s = Wf + (size_t)i * 8;
        f4 a = *(const f4*)s, b = *(const f4*)(s + 4);
        h8 v;
        v[0]=(_Float16)a[0]; v[1]=(_Float16)a[1]; v[2]=(_Float16)a[2]; v[3]=(_Float16)a[3];
        v[4]=(_Float16)b[0]; v[5]=(_Float16)b[1]; v[6]=(_Float16)b[2]; v[7]=(_Float16)b[3];
        *(h8*)(wf16 + (size_t)i * 8) = v;
    } else {                   // Wih1b pack-T: 49,152 items
        int i = (bid - 4144) * 256 + tid;
        int c = i % G_;
        int k2 = i / G_;
        wp[i] = __halves2half2(__float2half(W1b[c * 256 + 2 * k2]),
                               __float2half(W1b[c * 256 + 2 * k2 + 1]));
    }
}

// ---------------- Layer-0 scan: wave-specialized (unchanged from R8) ----------------
__launch_bounds__(768, 1)
__global__ void scan_l0(const _Float16* __restrict__ x16,
                        const float* __restrict__ Wih_f, const float* __restrict__ Whh_f,
                        const float* __restrict__ bih_f, const float* __restrict__ bhh_f,
                        const float* __restrict__ Wih_b, const float* __restrict__ Whh_b,
                        const float* __restrict__ bih_b, const float* __restrict__ bhh_b,
                        _Float16* __restrict__ out0) {
    __shared__ __align__(16) _Float16 s_h[2][16 * 128];
    __shared__ __align__(16) _Float16 s_x[2][16 * 64];

    const int tid  = threadIdx.x;
    const int lane = tid & 63;
    const int w    = tid >> 6;
    const int dir  = blockIdx.y;
    const int b0   = blockIdx.x * 16;

    const float* Wih = dir ? Wih_b : Wih_f;
    const float* Whh = dir ? Whh_b : Whh_f;
    const float* bih = dir ? bih_b : bih_f;
    const float* bhh = dir ? bhh_b : bhh_f;

    {
        for (int i = tid; i < 16 * 128; i += 768) s_h[0][i] = (_Float16)0.f;
        if (w >= 8) {
            int pt = tid - 512;
            if (pt < 128) {
                int xr = pt >> 3, xg = pt & 7;
                int t0 = dir ? (T_ - 1) : 0;
                h8 v = *(const h8*)(x16 + ((size_t)(b0 + xr) * T_ + t0) * I_ + xg * 8);
                *(h8*)&s_x[0][xr * 64 + ((xg ^ (xr & 7)) & 7) * 8] = v;
            }
        }
    }
    __syncthreads();

    if (w < 8) {   // ================= COMPUTE =================
        const int ln15 = lane & 15;
        const int lq   = lane >> 4;
        const int col  = 16 * w + ln15;
        h8 bh[3][4], bx[3][2];
        float seedR = bih[col] + bhh[col];
        float seedZ = bih[H_ + col] + bhh[H_ + col];
        float bihN  = bih[2 * H_ + col];
        float bhhN  = bhh[2 * H_ + col];
#pragma unroll
        for (int g = 0; g < 3; g++) {
            int n = g * H_ + col;
#pragma unroll
            for (int kt = 0; kt < 4; kt++) bh[g][kt] = load_w8(Whh + (size_t)n * H_ + kt * 32 + lq * 8);
#pragma unroll
            for (int kt = 0; kt < 2; kt++) bx[g][kt] = load_w8(Wih + (size_t)n * I_ + kt * 32 + lq * 8);
        }
        int offh[4], offx[2], offw[4];
#pragma unroll
        for (int kt = 0; kt < 4; kt++) offh[kt] = ln15 * 128 + (((kt * 4 + lq) ^ ln15) & 15) * 8;
#pragma unroll
        for (int kt = 0; kt < 2; kt++) offx[kt] = ln15 * 64 + (((kt * 4 + lq) ^ (ln15 & 7)) & 7) * 8;
#pragma unroll
        for (int reg = 0; reg < 4; reg++) {
            int row = lq * 4 + reg;
            offw[reg] = row * 128 + (((col >> 3) ^ row) & 15) * 8 + (col & 7);
        }
        float hF[4] = {0.f, 0.f, 0.f, 0.f};

#pragma unroll 1
        for (int t = 0; t < T_; t += 2) {
#pragma unroll
            for (int half_ = 0; half_ < 2; half_++) {
                h8 ah[4], axf[2];
#pragma unroll
                for (int kt = 0; kt < 4; kt++) ah[kt] = *(const h8*)&s_h[half_][offh[kt]];
#pragma unroll
                for (int kt = 0; kt < 2; kt++) axf[kt] = *(const h8*)&s_x[half_][offx[kt]];
                f4 aR  = (f4){seedR, seedR, seedR, seedR};
                f4 aZ  = (f4){seedZ, seedZ, seedZ, seedZ};
                f4 aXn = (f4){bihN, bihN, bihN, bihN};
                f4 aHn = (f4){bhhN, bhhN, bhhN, bhhN};
#pragma unroll
                for (int kt = 0; kt < 4; kt++) {
                    aR  = __builtin_amdgcn_mfma_f32_16x16x32_f16(ah[kt], bh[0][kt], aR, 0, 0, 0);
                    aZ  = __builtin_amdgcn_mfma_f32_16x16x32_f16(ah[kt], bh[1][kt], aZ, 0, 0, 0);
                    aHn = __builtin_amdgcn_mfma_f32_16x16x32_f16(ah[kt], bh[2][kt], aHn, 0, 0, 0);
                }
#pragma unroll
                for (int kt = 0; kt < 2; kt++) {
                    aR  = __builtin_amdgcn_mfma_f32_16x16x32_f16(axf[kt], bx[0][kt], aR, 0, 0, 0);
                    aZ  = __builtin_amdgcn_mfma_f32_16x16x32_f16(axf[kt], bx[1][kt], aZ, 0, 0, 0);
                    aXn = __builtin_amdgcn_mfma_f32_16x16x32_f16(axf[kt], bx[2][kt], aXn, 0, 0, 0);
                }
#pragma unroll
                for (int reg = 0; reg < 4; reg++) {
                    float r = sigm(aR[reg]);
                    float z = sigm(aZ[reg]);
                    float n = tanh_f(aXn[reg] + r * aHn[reg]);
                    float h = n + z * (hF[reg] - n);
                    hF[reg] = h;
                    s_h[half_ ^ 1][offw[reg]] = (_Float16)h;
                }
                bar_lds();
            }
        }
    } else {       // ================= PRODUCER =================
        const int pt = tid - 512;
        const int r  = pt >> 4;
        const int c8 = (pt & 15) * 8;
        const int roff = r * 128 + (((c8 >> 3) ^ r) & 15) * 8;
        _Float16* obase = out0 + ((size_t)(b0 + r) * T_) * HC + dir * H_ + c8;
        const int xr = pt >> 3, xg = pt & 7;
        const int xoff = xr * 64 + ((xg ^ (xr & 7)) & 7) * 8;
        const _Float16* xbase = x16 + ((size_t)(b0 + xr) * T_) * I_ + xg * 8;

#pragma unroll 1
        for (int t = 0; t < T_; t += 2) {
#pragma unroll
            for (int half_ = 0; half_ < 2; half_++) {
                int s = t + half_;
                if (s > 0) {
                    int ttp = dir ? (T_ - s) : (s - 1);
                    f4 hv = *(const f4*)&s_h[half_][roff];
                    *(f4*)(obase + (size_t)ttp * HC) = hv;
                }
                if (pt < 128 && s + 1 < T_) {
                    int tn = dir ? (T_ - 2 - s) : (s + 1);
                    h8 v = *(const h8*)(xbase + (size_t)tn * I_);
                    *(h8*)&s_x[half_ ^ 1][xoff] = v;
                }
                bar_lds();
            }
        }
        {
            int ttp = dir ? 0 : (T_ - 1);
            f4 hv = *(const f4*)&s_h[0][roff];
            *(f4*)(obase + (size_t)ttp * HC) = hv;
        }
    }
}

// ---------------- MFMA GEMM v3: double-buffered LDS, lgkm-only barriers ----------------
// fp16 A,B; BK=64; one bar_lds per chunk; prefetch chunk k+1 into regs before
// the MFMAs of chunk k so load latency hides under compute.
// Output rows gate-permuted: n<256 -> (n&127)*2+(n>>7); n>=256 -> n.
__launch_bounds__(256, 2)
__global__ void gemm_xw1(const _Float16* __restrict__ A,   // [M][256]
                         const _Float16* __restrict__ Bw,  // [384][256] fp16
                         const float* __restrict__ bias,
                         _Float16* __restrict__ C) {       // [M][384] permuted rows
    __shared__ __align__(16) _Float16 sA[2][128 * 64];
    __shared__ __align__(16) _Float16 sB[2][128 * 64];
    const int tid  = threadIdx.x;
    const int lane = tid & 63;
    const int w    = tid >> 6;
    const int wm   = w & 1, wn = w >> 1;
    const int ln15 = lane & 15, lq = lane >> 4;
    const int    n0 = blockIdx.x * 128;
    const size_t m0 = (size_t)blockIdx.y * 128;

    f4 acc[4][4] = {};

    int sRow[4], sG[4], sOff[4];
#pragma unroll
    for (int k = 0; k < 4; k++) {
        int idx = k * 256 + tid;
        sRow[k] = idx >> 3;
        sG[k]   = idx & 7;
        sOff[k] = sRow[k] * 64 + ((sG[k] ^ (sRow[k] & 7)) & 7) * 8;
    }
    int offA[4][2], offB[4][2];
#pragma unroll
    for (int mt = 0; mt < 4; mt++)
#pragma unroll
        for (int kt = 0; kt < 2; kt++) {
            int rowA = wm * 64 + mt * 16 + ln15;
            offA[mt][kt] = rowA * 64 + (((kt * 4 + lq) ^ (rowA & 7)) & 7) * 8;
            int rowB = wn * 64 + mt * 16 + ln15;
            offB[mt][kt] = rowB * 64 + (((kt * 4 + lq) ^ (rowB & 7)) & 7) * 8;
        }

    {   // prologue: chunk 0 -> buf 0
        h8 avp[4], bvp[4];
#pragma unroll
        for (int k = 0; k < 4; k++) {
            avp[k] = *(const h8*)(A + (m0 + sRow[k]) * 256 + sG[k] * 8);
            bvp[k] = *(const h8*)(Bw + (size_t)(n0 + sRow[k]) * 256 + sG[k] * 8);
        }
#pragma unroll
        for (int k = 0; k < 4; k++) {
            *(h8*)&sA[0][sOff[k]] = avp[k];
            *(h8*)&sB[0][sOff[k]] = bvp[k];
        }
        bar_lds();
    }

#pragma unroll
    for (int k0 = 0; k0 < 4; k0++) {
        const int cur = k0 & 1;
        h8 avn[4], bvn[4];
        if (k0 < 3) {   // issue prefetch of chunk k0+1 (latency hidden under MFMAs)
#pragma unroll
            for (int k = 0; k < 4; k++) {
                avn[k] = *(const h8*)(A + (m0 + sRow[k]) * 256 + (k0 + 1) * 64 + sG[k] * 8);
                bvn[k] = *(const h8*)(Bw + (size_t)(n0 + sRow[k]) * 256 + (k0 + 1) * 64 + sG[k] * 8);
            }
        }
#pragma unroll
        for (int kt = 0; kt < 2; kt++) {
            h8 af[4], bf[4];
#pragma unroll
            for (int mt = 0; mt < 4; mt++) af[mt] = *(const h8*)&sA[cur][offA[mt][kt]];
#pragma unroll
            for (int nt = 0; nt < 4; nt++) bf[nt] = *(const h8*)&sB[cur][offB[nt][kt]];
#pragma unroll
            for (int mt = 0; mt < 4; mt++)
#pragma unroll
                for (int nt = 0; nt < 4; nt++)
                    acc[mt][nt] = __builtin_amdgcn_mfma_f32_16x16x32_f16(af[mt], bf[nt], acc[mt][nt], 0, 0, 0);
        }
        if (k0 < 3) {
#pragma unroll
            for (int k = 0; k < 4; k++) {
                *(h8*)&sA[cur ^ 1][sOff[k]] = avn[k];
                *(h8*)&sB[cur ^ 1][sOff[k]] = bvn[k];
            }
            bar_lds();
        }
    }
#pragma unroll
    for (int nt = 0; nt < 4; nt++) {
        int col = n0 + wn * 64 + nt * 16 + ln15;
        float bb = bias[col];
        int pcol = (col < 256) ? ((col & 127) * 2 + (col >> 7)) : col;
#pragma unroll
        for (int mt = 0; mt < 4; mt++) {
            size_t row = m0 + wm * 64 + mt * 16 + lq * 4;
#pragma unroll
            for (int reg = 0; reg < 4; reg++)
                C[(row + reg) * G_ + pcol] = (_Float16)(acc[mt][nt][reg] + bb);
        }
    }
}

// ---------------- Layer-1 fwd scan: wave-specialized + ring (unchanged from R8) ----------------
#define RZP 268
#define NP  140
#define NB  (16 * RZP)
#define SLOT (NB + 16 * NP)
__launch_bounds__(768, 1)
__global__ void scan_l1(const _Float16* __restrict__ xw1,
                        const float* __restrict__ Whh,
                        const float* __restrict__ bhh,
                        float* __restrict__ h1f) {
    __shared__ __align__(16) _Float16 s_h[2][16 * 128];
    __shared__ __align__(16) _Float16 s_ring[2][SLOT];

    const int tid  = threadIdx.x;
    const int lane = tid & 63;
    const int w    = tid >> 6;
    const int b0   = blockIdx.x * 16;

    {
        for (int i = tid; i < 16 * 128; i += 768) s_h[0][i] = (_Float16)0.f;
    }

    if (w < 8) {   // ================= COMPUTE =================
        const int ln15 = lane & 15;
        const int lq   = lane >> 4;
        const int col  = 16 * w + ln15;
        h8 bh[3][4];
        float bhhF[3];
#pragma unroll
        for (int g = 0; g < 3; g++) {
            int n = g * H_ + col;
            bhhF[g] = bhh[n];
#pragma unroll
            for (int kt = 0; kt < 4; kt++) bh[g][kt] = load_w8(Whh + (size_t)n * H_ + kt * 32 + lq * 8);
        }
        int offh[4], offw[4], offrz[4], offn[4];
#pragma unroll
        for (int kt = 0; kt < 4; kt++) offh[kt] = ln15 * 128 + (((kt * 4 + lq) ^ ln15) & 15) * 8;
#pragma unroll
        for (int reg = 0; reg < 4; reg++) {
            int row = lq * 4 + reg;
            offw[reg]  = row * 128 + (((col >> 3) ^ row) & 15) * 8 + (col & 7);
            offrz[reg] = row * RZP + col * 2;
            offn[reg]  = NB + row * NP + col;
        }
        float hF[4] = {0.f, 0.f, 0.f, 0.f};
        __syncthreads();

#pragma unroll 1
        for (int t = 0; t < T_; t += 2) {
#pragma unroll
            for (int half_ = 0; half_ < 2; half_++) {
                h8 ah[4];
#pragma unroll
                for (int kt = 0; kt < 4; kt++) ah[kt] = *(const h8*)&s_h[half_][offh[kt]];
                f4 aH[3];
#pragma unroll
                for (int g = 0; g < 3; g++) aH[g] = (f4){bhhF[g], bhhF[g], bhhF[g], bhhF[g]};
#pragma unroll
                for (int kt = 0; kt < 4; kt++) {
                    aH[0] = __builtin_amdgcn_mfma_f32_16x16x32_f16(ah[kt], bh[0][kt], aH[0], 0, 0, 0);
                    aH[1] = __builtin_amdgcn_mfma_f32_16x16x32_f16(ah[kt], bh[1][kt], aH[1], 0, 0, 0);
                    aH[2] = __builtin_amdgcn_mfma_f32_16x16x32_f16(ah[kt], bh[2][kt], aH[2], 0, 0, 0);
                }
#pragma unroll
                for (int reg = 0; reg < 4; reg++) {
                    h2 rz = *(const h2*)&s_ring[half_][offrz[reg]];
                    float xn = (float)s_ring[half_][offn[reg]];
                    float r = sigm((float)rz[0] + aH[0][reg]);
                    float z = sigm((float)rz[1] + aH[1][reg]);
                    float n = tanh_f(xn + r * aH[2][reg]);
                    float h = n + z * (hF[reg] - n);
                    hF[reg] = h;
                    s_h[half_ ^ 1][offw[reg]] = (_Float16)h;
                }
                bar_lds();
            }
        }
#pragma unroll
        for (int reg = 0; reg < 4; reg++)
            h1f[(size_t)(b0 + lq * 4 + reg) * H_ + col] = hF[reg];
    } else {       // ================= PRODUCER (ring staging) =================
        const int pt = tid - 512;
        const _Float16* sgb[6];
        int dstoff[6];
#pragma unroll
        for (int k = 0; k < 6; k++) {
            int ch = pt + k * 256;
            int sRow = ch / 96;
            int c4 = (ch % 96) * 4;
            sgb[k] = xw1 + (size_t)(b0 + sRow) * T_ * G_ + c4;
            dstoff[k] = (c4 < 256) ? (sRow * RZP + c4) : (NB + sRow * NP + (c4 - 256));
        }
        float2 pfA[6], pfB[6];
#pragma unroll
        for (int k = 0; k < 6; k++) {
            float2 v = *(const float2*)(sgb[k]);
            *(float2*)&s_ring[0][dstoff[k]] = v;
            pfA[k] = *(const float2*)(sgb[k] + G_);
        }
        __syncthreads();

#pragma unroll 1
        for (int t = 0; t < T_; t += 2) {
            if (t + 2 < T_) {
#pragma unroll
                for (int k = 0; k < 6; k++) pfB[k] = *(const float2*)(sgb[k] + (size_t)(t + 2) * G_);
            }
#pragma unroll
            for (int k = 0; k < 6; k++) *(float2*)&s_ring[1][dstoff[k]] = pfA[k];
            bar_lds();
            if (t + 3 < T_) {
#pragma unroll
                for (int k = 0; k < 6; k++) pfA[k] = *(const float2*)(sgb[k] + (size_t)(t + 3) * G_);
            }
            if (t + 2 < T_) {
#pragma unroll
                for (int k = 0; k < 6; k++) *(float2*)&s_ring[0][dstoff[k]] = pfB[k];
            }
            bar_lds();
        }
    }
}

// ---------------- Tail: layer-1 bwd single step + relu + FC ----------------
__launch_bounds__(384)
__global__ void final_k(const _Float16* __restrict__ out0,
                        const float* __restrict__ h1f,
                        const __half2* __restrict__ w1b,
                        const float* __restrict__ bih1b, const float* __restrict__ bhh1b,
                        const float* __restrict__ fcw, const float* __restrict__ fcb,
                        float* __restrict__ out) {
    __shared__ __align__(16) float s_x1[HC];
    __shared__ __align__(16) float s_xw[G_];
    __shared__ __align__(16) float s_hc[HC];
    __shared__ float s_red[8];
    const int tid = threadIdx.x;
    const int b = blockIdx.x;
    if (tid < HC)
        s_x1[tid] = (float)out0[((size_t)b * T_ + (T_ - 1)) * HC + tid];
    __syncthreads();
    {
        float acc0 = 0.f, acc1 = 0.f;
        const float2* xv = (const float2*)s_x1;
#pragma unroll 8
        for (int k2 = 0; k2 < 128; k2 += 2) {
            float2 w0 = __half22float2(w1b[k2 * G_ + tid]);
            float2 w1 = __half22float2(w1b[(k2 + 1) * G_ + tid]);
            float2 a0 = xv[k2], a1 = xv[k2 + 1];
            acc0 += a0.x * w0.x + a0.y * w0.y;
            acc1 += a1.x * w1.x + a1.y * w1.y;
        }
        s_xw[tid] = bih1b[tid] + acc0 + acc1;
    }
    __syncthreads();
    if (tid < H_) {
        int j = tid;
        float rg = sigm(s_xw[j] + bhh1b[j]);
        float zg = sigm(s_xw[H_ + j] + bhh1b[H_ + j]);
        float ng = tanh_f(s_xw[2 * H_ + j] + rg * bhh1b[2 * H_ + j]);
        float hb = (1.f - zg) * ng;
        s_hc[H_ + j] = fmaxf(hb, 0.f);
        s_hc[j] = fmaxf(h1f[(size_t)b * H_ + j], 0.f);
    }
    __syncthreads();
    if (tid < HC) {
        float hv = s_hc[tid];
        float p0 = hv * fcw[tid];
        float p1 = hv * fcw[HC + tid];
#pragma unroll
        for (int off = 32; off; off >>= 1) {
            p0 += __shfl_down(p0, off);
            p1 += __shfl_down(p1, off);
        }
        if ((tid & 63) == 0) { s_red[(tid >> 6) * 2] = p0; s_red[(tid >> 6) * 2 + 1] = p1; }
    }
    __syncthreads();
    if (tid == 0) {
        out[b * 2 + 0] = fcb[0] + s_red[0] + s_red[2] + s_red[4] + s_red[6];
        out[b * 2 + 1] = fcb[1] + s_red[1] + s_red[3] + s_red[5] + s_red[7];
    }
}

extern "C" void kernel_launch(void* const* d_in, const int* in_sizes, int n_in,
                              void* d_out, int out_size, void* d_ws, size_t ws_size,
                              hipStream_t stream) {
    (void)in_sizes; (void)n_in; (void)out_size; (void)ws_size;
    const float* x     = (const float*)d_in[0];
    const float* Wih0f = (const float*)d_in[1];
    const float* Whh0f = (const float*)d_in[2];
    const float* bih0f = (const float*)d_in[3];
    const float* bhh0f = (const float*)d_in[4];
    const float* Wih0b = (const float*)d_in[5];
    const float* Whh0b = (const float*)d_in[6];
    const float* bih0b = (const float*)d_in[7];
    const float* bhh0b = (const float*)d_in[8];
    const float* Wih1f = (const float*)d_in[9];
    const float* Whh1f = (const float*)d_in[10];
    const float* bih1f = (const float*)d_in[11];
    const float* bhh1f = (const float*)d_in[12];
    const float* Wih1b = (const float*)d_in[13];
    const float* bih1b = (const float*)d_in[15];
    const float* bhh1b = (const float*)d_in[16];
    const float* fcw   = (const float*)d_in[17];
    const float* fcb   = (const float*)d_in[18];

    char* ws = (char*)d_ws;
    _Float16* out0 = (_Float16*)(ws + O_OUT0);
    _Float16* xw1  = (_Float16*)(ws + O_XW1);
    _Float16* x16  = (_Float16*)(ws + O_X16);
    __half2*  wp   = (__half2*)(ws + O_WP);
    float*    h1f  = (float*)(ws + O_H1F);
    _Float16* wf16 = (_Float16*)(ws + O_WF16);
    float*    out  = (float*)d_out;

    prep<<<4336, 256, 0, stream>>>(x, x16, Wih1f, wf16, Wih1b, wp);

    scan_l0<<<dim3(16, 2), 768, 0, stream>>>(x16, Wih0f, Whh0f, bih0f, bhh0f,
                                             Wih0b, Whh0b, bih0b, bhh0b, out0);

    gemm_xw1<<<dim3(3, 1024), 256, 0, stream>>>(out0, wf16, bih1f, xw1);

    scan_l1<<<16, 768, 0, stream>>>(xw1, Whh1f, bhh1f, h1f);

    final_k<<<256, 384, 0, stream>>>(out0, h1f, wp, bih1b, bhh1b, fcw, fcb, out);
}

// Round 10
// 821.687 us; speedup vs baseline: 4.0448x; 1.0016x over previous
//
#include <hip/hip_runtime.h>
#include <hip/hip_fp16.h>

#define B_  256
#define T_  512
#define I_  64
#define H_  128
#define G_  384
#define HC  256

// Workspace layout (stream-ordered aliasing: x16 occupies the head of the xw1
// region — gemm overwrites it only after scan_l0 has fully consumed x16).
#define O_OUT0 0ull                    // fp16 [B][T][2H] = 67,108,864
#define O_XW1  67108864ull             // fp16 [B][T][3H] = 100,663,296 (xw1; x16 aliases head)
#define O_X16  O_XW1                   // fp16 [B][T][64] = 16,777,216 (until gemm runs)
#define O_WP   167772160ull            // packed half2 Wih1b, 196,608
#define O_H1F  (O_WP + 196608ull)      // f32 [B][H] = 131,072
#define O_WF16 (O_H1F + 131072ull)     // fp16 Wih1f [384][256] = 196,608

typedef _Float16 h8 __attribute__((ext_vector_type(8)));
typedef _Float16 h2 __attribute__((ext_vector_type(2)));
typedef float    f4 __attribute__((ext_vector_type(4)));

__device__ __forceinline__ float sigm(float x)   { return __builtin_amdgcn_rcpf(1.f + __expf(-x)); }
__device__ __forceinline__ float tanh_f(float x) { return 1.f - 2.f * __builtin_amdgcn_rcpf(1.f + __expf(2.f * x)); }

// LDS-only barrier: waits lgkmcnt(0) but NOT vmcnt.
__device__ __forceinline__ void bar_lds() {
    asm volatile("s_waitcnt lgkmcnt(0)\n\ts_barrier" ::: "memory");
}

__device__ __forceinline__ h8 load_w8(const float* src) {
    f4 a = *(const f4*)src;
    f4 b = *(const f4*)(src + 4);
    h8 v;
    v[0]=(_Float16)a[0]; v[1]=(_Float16)a[1]; v[2]=(_Float16)a[2]; v[3]=(_Float16)a[3];
    v[4]=(_Float16)b[0]; v[5]=(_Float16)b[1]; v[6]=(_Float16)b[2]; v[7]=(_Float16)b[3];
    return v;
}

// Fused prep: x->fp16 (4096 blocks), Wih1f->fp16 (48), Wih1b pack-T (192).
__global__ void prep(const float* __restrict__ x, _Float16* __restrict__ x16,
                     const float* __restrict__ Wf, _Float16* __restrict__ wf16,
                     const float* __restrict__ W1b, __half2* __restrict__ wp) {
    const int bid = blockIdx.x;
    const int tid = threadIdx.x;
    if (bid < 4096) {          // x: 1,048,576 groups of 8
        int i = bid * 256 + tid;
        const float* s = x + (size_t)i * 8;
        f4 a = *(const f4*)s, b = *(const f4*)(s + 4);
        h8 v;
        v[0]=(_Float16)a[0]; v[1]=(_Float16)a[1]; v[2]=(_Float16)a[2]; v[3]=(_Float16)a[3];
        v[4]=(_Float16)b[0]; v[5]=(_Float16)b[1]; v[6]=(_Float16)b[2]; v[7]=(_Float16)b[3];
        *(h8*)(x16 + (size_t)i * 8) = v;
    } else if (bid < 4144) {   // Wih1f: 12,288 groups of 8
        int i = (bid - 4096) * 256 + tid;
        const float* s = Wf + (size_t)i * 8;
        f4 a = *(const f4*)s, b = *(const f4*)(s + 4);
        h8 v;
        v[0]=(_Float16)a[0]; v[1]=(_Float16)a[1]; v[2]=(_Float16)a[2]; v[3]=(_Float16)a[3];
        v[4]=(_Float16)b[0]; v[5]=(_Float16)b[1]; v[6]=(_Float16)b[2]; v[7]=(_Float16)b[3];
        *(h8*)(wf16 + (size_t)i * 8) = v;
    } else {                   // Wih1b pack-T: 49,152 items
        int i = (bid - 4144) * 256 + tid;
        int c = i % G_;
        int k2 = i / G_;
        wp[i] = __halves2half2(__float2half(W1b[c * 256 + 2 * k2]),
                               __float2half(W1b[c * 256 + 2 * k2 + 1]));
    }
}

// ---------------- Layer-0 scan: wave-specialized, distance-1 x prefetch ----------------
__launch_bounds__(768, 1)
__global__ void scan_l0(const _Float16* __restrict__ x16,
                        const float* __restrict__ Wih_f, const float* __restrict__ Whh_f,
                        const float* __restrict__ bih_f, const float* __restrict__ bhh_f,
                        const float* __restrict__ Wih_b, const float* __restrict__ Whh_b,
                        const float* __restrict__ bih_b, const float* __restrict__ bhh_b,
                        _Float16* __restrict__ out0) {
    __shared__ __align__(16) _Float16 s_h[2][16 * 128];
    __shared__ __align__(16) _Float16 s_x[2][16 * 64];

    const int tid  = threadIdx.x;
    const int lane = tid & 63;
    const int w    = tid >> 6;
    const int dir  = blockIdx.y;
    const int b0   = blockIdx.x * 16;

    const float* Wih = dir ? Wih_b : Wih_f;
    const float* Whh = dir ? Whh_b : Whh_f;
    const float* bih = dir ? bih_b : bih_f;
    const float* bhh = dir ? bhh_b : bhh_f;

    {
        for (int i = tid; i < 16 * 128; i += 768) s_h[0][i] = (_Float16)0.f;
        if (w >= 8) {
            int pt = tid - 512;
            if (pt < 128) {
                int xr = pt >> 3, xg = pt & 7;
                int t0 = dir ? (T_ - 1) : 0;
                h8 v = *(const h8*)(x16 + ((size_t)(b0 + xr) * T_ + t0) * I_ + xg * 8);
                *(h8*)&s_x[0][xr * 64 + ((xg ^ (xr & 7)) & 7) * 8] = v;
            }
        }
    }
    __syncthreads();

    if (w < 8) {   // ================= COMPUTE =================
        const int ln15 = lane & 15;
        const int lq   = lane >> 4;
        const int col  = 16 * w + ln15;
        h8 bh[3][4], bx[3][2];
        float seedR = bih[col] + bhh[col];
        float seedZ = bih[H_ + col] + bhh[H_ + col];
        float bihN  = bih[2 * H_ + col];
        float bhhN  = bhh[2 * H_ + col];
#pragma unroll
        for (int g = 0; g < 3; g++) {
            int n = g * H_ + col;
#pragma unroll
            for (int kt = 0; kt < 4; kt++) bh[g][kt] = load_w8(Whh + (size_t)n * H_ + kt * 32 + lq * 8);
#pragma unroll
            for (int kt = 0; kt < 2; kt++) bx[g][kt] = load_w8(Wih + (size_t)n * I_ + kt * 32 + lq * 8);
        }
        int offh[4], offx[2], offw[4];
#pragma unroll
        for (int kt = 0; kt < 4; kt++) offh[kt] = ln15 * 128 + (((kt * 4 + lq) ^ ln15) & 15) * 8;
#pragma unroll
        for (int kt = 0; kt < 2; kt++) offx[kt] = ln15 * 64 + (((kt * 4 + lq) ^ (ln15 & 7)) & 7) * 8;
#pragma unroll
        for (int reg = 0; reg < 4; reg++) {
            int row = lq * 4 + reg;
            offw[reg] = row * 128 + (((col >> 3) ^ row) & 15) * 8 + (col & 7);
        }
        float hF[4] = {0.f, 0.f, 0.f, 0.f};

#pragma unroll 1
        for (int t = 0; t < T_; t += 2) {
#pragma unroll
            for (int half_ = 0; half_ < 2; half_++) {
                h8 ah[4], axf[2];
#pragma unroll
                for (int kt = 0; kt < 4; kt++) ah[kt] = *(const h8*)&s_h[half_][offh[kt]];
#pragma unroll
                for (int kt = 0; kt < 2; kt++) axf[kt] = *(const h8*)&s_x[half_][offx[kt]];
                f4 aR  = (f4){seedR, seedR, seedR, seedR};
                f4 aZ  = (f4){seedZ, seedZ, seedZ, seedZ};
                f4 aXn = (f4){bihN, bihN, bihN, bihN};
                f4 aHn = (f4){bhhN, bhhN, bhhN, bhhN};
#pragma unroll
                for (int kt = 0; kt < 4; kt++) {
                    aR  = __builtin_amdgcn_mfma_f32_16x16x32_f16(ah[kt], bh[0][kt], aR, 0, 0, 0);
                    aZ  = __builtin_amdgcn_mfma_f32_16x16x32_f16(ah[kt], bh[1][kt], aZ, 0, 0, 0);
                    aHn = __builtin_amdgcn_mfma_f32_16x16x32_f16(ah[kt], bh[2][kt], aHn, 0, 0, 0);
                }
#pragma unroll
                for (int kt = 0; kt < 2; kt++) {
                    aR  = __builtin_amdgcn_mfma_f32_16x16x32_f16(axf[kt], bx[0][kt], aR, 0, 0, 0);
                    aZ  = __builtin_amdgcn_mfma_f32_16x16x32_f16(axf[kt], bx[1][kt], aZ, 0, 0, 0);
                    aXn = __builtin_amdgcn_mfma_f32_16x16x32_f16(axf[kt], bx[2][kt], aXn, 0, 0, 0);
                }
#pragma unroll
                for (int reg = 0; reg < 4; reg++) {
                    float r = sigm(aR[reg]);
                    float z = sigm(aZ[reg]);
                    float n = tanh_f(aXn[reg] + r * aHn[reg]);
                    float h = n + z * (hF[reg] - n);
                    hF[reg] = h;
                    s_h[half_ ^ 1][offw[reg]] = (_Float16)h;
                }
                bar_lds();
            }
        }
    } else {       // ================= PRODUCER =================
        const int pt = tid - 512;
        const int r  = pt >> 4;
        const int c8 = (pt & 15) * 8;
        const int roff = r * 128 + (((c8 >> 3) ^ r) & 15) * 8;
        _Float16* obase = out0 + ((size_t)(b0 + r) * T_) * HC + dir * H_ + c8;
        const int xr = pt >> 3, xg = pt & 7;
        const int xoff = xr * 64 + ((xg ^ (xr & 7)) & 7) * 8;
        const _Float16* xbase = x16 + ((size_t)(b0 + xr) * T_) * I_ + xg * 8;

        h8 pfA = {}, pfB = {};
        if (pt < 128) {   // prologue: pfA = x(step 1)
            int tn = dir ? (T_ - 2) : 1;
            pfA = *(const h8*)(xbase + (size_t)tn * I_);
        }

#pragma unroll 1
        for (int t = 0; t < T_; t += 2) {
            {   // even step s=t: x write for s+1 (always valid), load x(s+2)
                if (pt < 128) {
                    *(h8*)&s_x[1][xoff] = pfA;
                    if (t + 2 < T_) {
                        int tn = dir ? (T_ - 3 - t) : (t + 2);
                        pfB = *(const h8*)(xbase + (size_t)tn * I_);
                    }
                }
                if (t > 0) {
                    int ttp = dir ? (T_ - t) : (t - 1);
                    f4 hv = *(const f4*)&s_h[0][roff];
                    *(f4*)(obase + (size_t)ttp * HC) = hv;
                }
                bar_lds();
            }
            {   // odd step s=t+1: x write for s+1=t+2 (if exists), load x(t+3)
                if (pt < 128) {
                    if (t + 2 < T_) *(h8*)&s_x[0][xoff] = pfB;
                    if (t + 3 < T_) {
                        int tn = dir ? (T_ - 4 - t) : (t + 3);
                        pfA = *(const h8*)(xbase + (size_t)tn * I_);
                    }
                }
                {
                    int s = t + 1;
                    int ttp = dir ? (T_ - s) : (s - 1);
                    f4 hv = *(const f4*)&s_h[1][roff];
                    *(f4*)(obase + (size_t)ttp * HC) = hv;
                }
                bar_lds();
            }
        }
        {   // epilogue: store h(T) (in s_h[0]) @ time tt(T-1)
            int ttp = dir ? 0 : (T_ - 1);
            f4 hv = *(const f4*)&s_h[0][roff];
            *(f4*)(obase + (size_t)ttp * HC) = hv;
        }
    }
}

// ---------------- MFMA GEMM v4: per-block M=64, full N=384 ----------------
// A (out0, 67 MB) read exactly ONCE from HBM; B (196 KB) L2-hot across blocks.
// K=256 in 4 chunks of 64; LDS dbuf 112 KB; reg prefetch; lgkm-only barriers.
// Output rows gate-permuted: n<256 -> (n&127)*2+(n>>7); n>=256 -> n.
__launch_bounds__(256, 1)
__global__ void gemm_xw1(const _Float16* __restrict__ A,   // [M][256]
                         const _Float16* __restrict__ Bw,  // [384][256] fp16
                         const float* __restrict__ bias,
                         _Float16* __restrict__ C) {       // [M][384] permuted rows
    __shared__ __align__(16) _Float16 sA[2][64 * 64];
    __shared__ __align__(16) _Float16 sB[2][384 * 64];
    const int tid  = threadIdx.x;
    const int lane = tid & 63;
    const int w    = tid >> 6;
    const int wm   = w & 1, wn = w >> 1;      // M-half (32 rows), N-half (192 cols)
    const int ln15 = lane & 15, lq = lane >> 4;
    const size_t m0 = (size_t)blockIdx.x * 64;

    f4 acc[2][12] = {};

    // staging maps (granule = 8 halfs)
    int aRow[2], aG[2], aOff[2];
#pragma unroll
    for (int k = 0; k < 2; k++) {
        int idx = k * 256 + tid;               // 512 granules: 64 rows x 8
        aRow[k] = idx >> 3; aG[k] = idx & 7;
        aOff[k] = aRow[k] * 64 + ((aG[k] ^ (aRow[k] & 7)) & 7) * 8;
    }
    int bRow[12], bG[12], bOff[12];
#pragma unroll
    for (int k = 0; k < 12; k++) {
        int idx = k * 256 + tid;               // 3072 granules: 384 rows x 8
        bRow[k] = idx >> 3; bG[k] = idx & 7;
        bOff[k] = bRow[k] * 64 + ((bG[k] ^ (bRow[k] & 7)) & 7) * 8;
    }
    int offA[2][2], offB[12][2];
#pragma unroll
    for (int mt = 0; mt < 2; mt++)
#pragma unroll
        for (int kt = 0; kt < 2; kt++) {
            int row = wm * 32 + mt * 16 + ln15;
            offA[mt][kt] = row * 64 + (((kt * 4 + lq) ^ (row & 7)) & 7) * 8;
        }
#pragma unroll
    for (int nt = 0; nt < 12; nt++)
#pragma unroll
        for (int kt = 0; kt < 2; kt++) {
            int row = wn * 192 + nt * 16 + ln15;
            offB[nt][kt] = row * 64 + (((kt * 4 + lq) ^ (row & 7)) & 7) * 8;
        }

    {   // prologue: chunk 0 -> buf 0
        h8 av[2], bv[12];
#pragma unroll
        for (int k = 0; k < 2; k++) av[k] = *(const h8*)(A + (m0 + aRow[k]) * 256 + aG[k] * 8);
#pragma unroll
        for (int k = 0; k < 12; k++) bv[k] = *(const h8*)(Bw + (size_t)bRow[k] * 256 + bG[k] * 8);
#pragma unroll
        for (int k = 0; k < 2; k++) *(h8*)&sA[0][aOff[k]] = av[k];
#pragma unroll
        for (int k = 0; k < 12; k++) *(h8*)&sB[0][bOff[k]] = bv[k];
        bar_lds();
    }

#pragma unroll
    for (int c = 0; c < 4; c++) {
        const int cur = c & 1;
        h8 av[2], bv[12];
        if (c < 3) {   // prefetch chunk c+1 (latency hidden under 48 MFMAs)
#pragma unroll
            for (int k = 0; k < 2; k++)
                av[k] = *(const h8*)(A + (m0 + aRow[k]) * 256 + (c + 1) * 64 + aG[k] * 8);
#pragma unroll
            for (int k = 0; k < 12; k++)
                bv[k] = *(const h8*)(Bw + (size_t)bRow[k] * 256 + (c + 1) * 64 + bG[k] * 8);
        }
#pragma unroll
        for (int kt = 0; kt < 2; kt++) {
            h8 af0 = *(const h8*)&sA[cur][offA[0][kt]];
            h8 af1 = *(const h8*)&sA[cur][offA[1][kt]];
#pragma unroll
            for (int nt = 0; nt < 12; nt++) {
                h8 bf = *(const h8*)&sB[cur][offB[nt][kt]];
                acc[0][nt] = __builtin_amdgcn_mfma_f32_16x16x32_f16(af0, bf, acc[0][nt], 0, 0, 0);
                acc[1][nt] = __builtin_amdgcn_mfma_f32_16x16x32_f16(af1, bf, acc[1][nt], 0, 0, 0);
            }
        }
        if (c < 3) {
#pragma unroll
            for (int k = 0; k < 2; k++) *(h8*)&sA[cur ^ 1][aOff[k]] = av[k];
#pragma unroll
            for (int k = 0; k < 12; k++) *(h8*)&sB[cur ^ 1][bOff[k]] = bv[k];
            bar_lds();
        }
    }
#pragma unroll
    for (int nt = 0; nt < 12; nt++) {
        int col = wn * 192 + nt * 16 + ln15;
        float bb = bias[col];
        int pcol = (col < 256) ? ((col & 127) * 2 + (col >> 7)) : col;
#pragma unroll
        for (int mt = 0; mt < 2; mt++) {
            size_t row = m0 + wm * 32 + mt * 16 + lq * 4;
#pragma unroll
            for (int reg = 0; reg < 4; reg++)
                C[(row + reg) * G_ + pcol] = (_Float16)(acc[mt][nt][reg] + bb);
        }
    }
}

// ---------------- Layer-1 fwd scan: wave-specialized + ring (unchanged) ----------------
#define RZP 268
#define NP  140
#define NB  (16 * RZP)
#define SLOT (NB + 16 * NP)
__launch_bounds__(768, 1)
__global__ void scan_l1(const _Float16* __restrict__ xw1,
                        const float* __restrict__ Whh,
                        const float* __restrict__ bhh,
                        float* __restrict__ h1f) {
    __shared__ __align__(16) _Float16 s_h[2][16 * 128];
    __shared__ __align__(16) _Float16 s_ring[2][SLOT];

    const int tid  = threadIdx.x;
    const int lane = tid & 63;
    const int w    = tid >> 6;
    const int b0   = blockIdx.x * 16;

    {
        for (int i = tid; i < 16 * 128; i += 768) s_h[0][i] = (_Float16)0.f;
    }

    if (w < 8) {   // ================= COMPUTE =================
        const int ln15 = lane & 15;
        const int lq   = lane >> 4;
        const int col  = 16 * w + ln15;
        h8 bh[3][4];
        float bhhF[3];
#pragma unroll
        for (int g = 0; g < 3; g++) {
            int n = g * H_ + col;
            bhhF[g] = bhh[n];
#pragma unroll
            for (int kt = 0; kt < 4; kt++) bh[g][kt] = load_w8(Whh + (size_t)n * H_ + kt * 32 + lq * 8);
        }
        int offh[4], offw[4], offrz[4], offn[4];
#pragma unroll
        for (int kt = 0; kt < 4; kt++) offh[kt] = ln15 * 128 + (((kt * 4 + lq) ^ ln15) & 15) * 8;
#pragma unroll
        for (int reg = 0; reg < 4; reg++) {
            int row = lq * 4 + reg;
            offw[reg]  = row * 128 + (((col >> 3) ^ row) & 15) * 8 + (col & 7);
            offrz[reg] = row * RZP + col * 2;
            offn[reg]  = NB + row * NP + col;
        }
        float hF[4] = {0.f, 0.f, 0.f, 0.f};
        __syncthreads();

#pragma unroll 1
        for (int t = 0; t < T_; t += 2) {
#pragma unroll
            for (int half_ = 0; half_ < 2; half_++) {
                h8 ah[4];
#pragma unroll
                for (int kt = 0; kt < 4; kt++) ah[kt] = *(const h8*)&s_h[half_][offh[kt]];
                f4 aH[3];
#pragma unroll
                for (int g = 0; g < 3; g++) aH[g] = (f4){bhhF[g], bhhF[g], bhhF[g], bhhF[g]};
#pragma unroll
                for (int kt = 0; kt < 4; kt++) {
                    aH[0] = __builtin_amdgcn_mfma_f32_16x16x32_f16(ah[kt], bh[0][kt], aH[0], 0, 0, 0);
                    aH[1] = __builtin_amdgcn_mfma_f32_16x16x32_f16(ah[kt], bh[1][kt], aH[1], 0, 0, 0);
                    aH[2] = __builtin_amdgcn_mfma_f32_16x16x32_f16(ah[kt], bh[2][kt], aH[2], 0, 0, 0);
                }
#pragma unroll
                for (int reg = 0; reg < 4; reg++) {
                    h2 rz = *(const h2*)&s_ring[half_][offrz[reg]];
                    float xn = (float)s_ring[half_][offn[reg]];
                    float r = sigm((float)rz[0] + aH[0][reg]);
                    float z = sigm((float)rz[1] + aH[1][reg]);
                    float n = tanh_f(xn + r * aH[2][reg]);
                    float h = n + z * (hF[reg] - n);
                    hF[reg] = h;
                    s_h[half_ ^ 1][offw[reg]] = (_Float16)h;
                }
                bar_lds();
            }
        }
#pragma unroll
        for (int reg = 0; reg < 4; reg++)
            h1f[(size_t)(b0 + lq * 4 + reg) * H_ + col] = hF[reg];
    } else {       // ================= PRODUCER (ring staging) =================
        const int pt = tid - 512;
        const _Float16* sgb[6];
        int dstoff[6];
#pragma unroll
        for (int k = 0; k < 6; k++) {
            int ch = pt + k * 256;
            int sRow = ch / 96;
            int c4 = (ch % 96) * 4;
            sgb[k] = xw1 + (size_t)(b0 + sRow) * T_ * G_ + c4;
            dstoff[k] = (c4 < 256) ? (sRow * RZP + c4) : (NB + sRow * NP + (c4 - 256));
        }
        float2 pfA[6], pfB[6];
#pragma unroll
        for (int k = 0; k < 6; k++) {
            float2 v = *(const float2*)(sgb[k]);
            *(float2*)&s_ring[0][dstoff[k]] = v;
            pfA[k] = *(const float2*)(sgb[k] + G_);
        }
        __syncthreads();

#pragma unroll 1
        for (int t = 0; t < T_; t += 2) {
            if (t + 2 < T_) {
#pragma unroll
                for (int k = 0; k < 6; k++) pfB[k] = *(const float2*)(sgb[k] + (size_t)(t + 2) * G_);
            }
#pragma unroll
            for (int k = 0; k < 6; k++) *(float2*)&s_ring[1][dstoff[k]] = pfA[k];
            bar_lds();
            if (t + 3 < T_) {
#pragma unroll
                for (int k = 0; k < 6; k++) pfA[k] = *(const float2*)(sgb[k] + (size_t)(t + 3) * G_);
            }
            if (t + 2 < T_) {
#pragma unroll
                for (int k = 0; k < 6; k++) *(float2*)&s_ring[0][dstoff[k]] = pfB[k];
            }
            bar_lds();
        }
    }
}

// ---------------- Tail: layer-1 bwd single step + relu + FC ----------------
__launch_bounds__(384)
__global__ void final_k(const _Float16* __restrict__ out0,
                        const float* __restrict__ h1f,
                        const __half2* __restrict__ w1b,
                        const float* __restrict__ bih1b, const float* __restrict__ bhh1b,
                        const float* __restrict__ fcw, const float* __restrict__ fcb,
                        float* __restrict__ out) {
    __shared__ __align__(16) float s_x1[HC];
    __shared__ __align__(16) float s_xw[G_];
    __shared__ __align__(16) float s_hc[HC];
    __shared__ float s_red[8];
    const int tid = threadIdx.x;
    const int b = blockIdx.x;
    if (tid < HC)
        s_x1[tid] = (float)out0[((size_t)b * T_ + (T_ - 1)) * HC + tid];
    __syncthreads();
    {
        float acc0 = 0.f, acc1 = 0.f;
        const float2* xv = (const float2*)s_x1;
#pragma unroll 8
        for (int k2 = 0; k2 < 128; k2 += 2) {
            float2 w0 = __half22float2(w1b[k2 * G_ + tid]);
            float2 w1 = __half22float2(w1b[(k2 + 1) * G_ + tid]);
            float2 a0 = xv[k2], a1 = xv[k2 + 1];
            acc0 += a0.x * w0.x + a0.y * w0.y;
            acc1 += a1.x * w1.x + a1.y * w1.y;
        }
        s_xw[tid] = bih1b[tid] + acc0 + acc1;
    }
    __syncthreads();
    if (tid < H_) {
        int j = tid;
        float rg = sigm(s_xw[j] + bhh1b[j]);
        float zg = sigm(s_xw[H_ + j] + bhh1b[H_ + j]);
        float ng = tanh_f(s_xw[2 * H_ + j] + rg * bhh1b[2 * H_ + j]);
        float hb = (1.f - zg) * ng;
        s_hc[H_ + j] = fmaxf(hb, 0.f);
        s_hc[j] = fmaxf(h1f[(size_t)b * H_ + j], 0.f);
    }
    __syncthreads();
    if (tid < HC) {
        float hv = s_hc[tid];
        float p0 = hv * fcw[tid];
        float p1 = hv * fcw[HC + tid];
#pragma unroll
        for (int off = 32; off; off >>= 1) {
            p0 += __shfl_down(p0, off);
            p1 += __shfl_down(p1, off);
        }
        if ((tid & 63) == 0) { s_red[(tid >> 6) * 2] = p0; s_red[(tid >> 6) * 2 + 1] = p1; }
    }
    __syncthreads();
    if (tid == 0) {
        out[b * 2 + 0] = fcb[0] + s_red[0] + s_red[2] + s_red[4] + s_red[6];
        out[b * 2 + 1] = fcb[1] + s_red[1] + s_red[3] + s_red[5] + s_red[7];
    }
}

extern "C" void kernel_launch(void* const* d_in, const int* in_sizes, int n_in,
                              void* d_out, int out_size, void* d_ws, size_t ws_size,
                              hipStream_t stream) {
    (void)in_sizes; (void)n_in; (void)out_size; (void)ws_size;
    const float* x     = (const float*)d_in[0];
    const float* Wih0f = (const float*)d_in[1];
    const float* Whh0f = (const float*)d_in[2];
    const float* bih0f = (const float*)d_in[3];
    const float* bhh0f = (const float*)d_in[4];
    const float* Wih0b = (const float*)d_in[5];
    const float* Whh0b = (const float*)d_in[6];
    const float* bih0b = (const float*)d_in[7];
    const float* bhh0b = (const float*)d_in[8];
    const float* Wih1f = (const float*)d_in[9];
    const float* Whh1f = (const float*)d_in[10];
    const float* bih1f = (const float*)d_in[11];
    const float* bhh1f = (const float*)d_in[12];
    const float* Wih1b = (const float*)d_in[13];
    const float* bih1b = (const float*)d_in[15];
    const float* bhh1b = (const float*)d_in[16];
    const float* fcw   = (const float*)d_in[17];
    const float* fcb   = (const float*)d_in[18];

    char* ws = (char*)d_ws;
    _Float16* out0 = (_Float16*)(ws + O_OUT0);
    _Float16* xw1  = (_Float16*)(ws + O_XW1);
    _Float16* x16  = (_Float16*)(ws + O_X16);
    __half2*  wp   = (__half2*)(ws + O_WP);
    float*    h1f  = (float*)(ws + O_H1F);
    _Float16* wf16 = (_Float16*)(ws + O_WF16);
    float*    out  = (float*)d_out;

    prep<<<4336, 256, 0, stream>>>(x, x16, Wih1f, wf16, Wih1b, wp);

    scan_l0<<<dim3(16, 2), 768, 0, stream>>>(x16, Wih0f, Whh0f, bih0f, bhh0f,
                                             Wih0b, Whh0b, bih0b, bhh0b, out0);

    gemm_xw1<<<2048, 256, 0, stream>>>(out0, wf16, bih1f, xw1);

    scan_l1<<<16, 768, 0, stream>>>(xw1, Whh1f, bhh1f, h1f);

    final_k<<<256, 384, 0, stream>>>(out0, h1f, wp, bih1b, bhh1b, fcw, fcb, out);
}